// Round 1
// baseline (3997.464 us; speedup 1.0000x reference)
//
#include <hip/hip_runtime.h>
#include <hip/hip_bf16.h>
#include <math.h>

// Problem constants
#define CC 8
#define FF 1024
#define WW 512
#define HH 16
#define DD 64
#define FE 4096   // F*EXP
#define EPS_ 1e-5f

// ---------------------------------------------------------------------------
// frame_norm: normalize over F (axis 2) per (c,w) column. x layout (c,f,w).
// grid: (W/64, C), block 256 = 64 w-lanes x 4 f-groups
// ---------------------------------------------------------------------------
__global__ __launch_bounds__(256) void frame_norm_k(
    const float* __restrict__ x, const float* __restrict__ g,
    const float* __restrict__ b, float* __restrict__ z)
{
    int c  = blockIdx.y;
    int w0 = blockIdx.x * 64;
    int t  = threadIdx.x;
    int wl = t & 63;
    int fg = t >> 6;           // 0..3
    const float* xc = x + (size_t)c * FF * WW;
    float*       zc = z + (size_t)c * FF * WW;

    float sum = 0.f, sq = 0.f;
    for (int f = fg; f < FF; f += 4) {
        float v = xc[(size_t)f * WW + w0 + wl];
        sum += v; sq += v * v;
    }
    __shared__ float ssum[4][64], ssq[4][64], smu[64], srv[64];
    ssum[fg][wl] = sum; ssq[fg][wl] = sq;
    __syncthreads();
    if (fg == 0) {
        float s = 0.f, q = 0.f;
        #pragma unroll
        for (int j = 0; j < 4; j++) { s += ssum[j][wl]; q += ssq[j][wl]; }
        float mu  = s * (1.f / FF);
        float var = q * (1.f / FF) - mu * mu;
        smu[wl] = mu;
        srv[wl] = rsqrtf(var + EPS_);
    }
    __syncthreads();
    float mu = smu[wl], rv = srv[wl];
    for (int f = fg; f < FF; f += 4) {
        float v = xc[(size_t)f * WW + w0 + wl];
        zc[(size_t)f * WW + w0 + wl] = (v - mu) * rv * g[f] + b[f];
    }
}

// ---------------------------------------------------------------------------
// Per-channel GEMM: Out[c,m,n] = sum_k Wt[c,m,k] * X[c,k,n]  (+addsrc, +act)
// Wt: (C, M, K) row-major (k contiguous); X: (C, K, N) (n contiguous)
// 64x64 tile, 256 threads, 4x4 per thread, K-chunk 16.
// act: 0 = none, 1 = exact GELU
// ---------------------------------------------------------------------------
__device__ inline float gelu_exact(float v) {
    return 0.5f * v * (1.0f + erff(v * 0.70710678118654752f));
}

__global__ __launch_bounds__(256) void gemm_ck(
    const float* __restrict__ Wt, const float* __restrict__ X,
    float* __restrict__ Out, const float* __restrict__ addsrc,
    int M, int K, int N, int act)
{
    int c  = blockIdx.z;
    int m0 = blockIdx.y * 64;
    int n0 = blockIdx.x * 64;
    const float* A = Wt + (size_t)c * M * K;
    const float* B = X  + (size_t)c * K * N;

    __shared__ float sA[16][65];  // [k][m], padded
    __shared__ float sB[16][64];  // [k][n]

    int t  = threadIdx.x;
    int tx = t & 15;        // n-group
    int ty = t >> 4;        // m-group

    float acc[4][4] = {{0.f}};

    int kk = t & 15;
    int mi = t >> 4;
    int nn = t & 63;
    int kb = t >> 6;

    for (int k0 = 0; k0 < K; k0 += 16) {
        #pragma unroll
        for (int r = 0; r < 4; r++)
            sA[kk][mi + 16 * r] = A[(size_t)(m0 + mi + 16 * r) * K + k0 + kk];
        #pragma unroll
        for (int r = 0; r < 4; r++)
            sB[kb + 4 * r][nn] = B[(size_t)(k0 + kb + 4 * r) * N + n0 + nn];
        __syncthreads();
        #pragma unroll
        for (int k2 = 0; k2 < 16; k2++) {
            float ra[4], rb[4];
            #pragma unroll
            for (int a = 0; a < 4; a++) ra[a] = sA[k2][ty * 4 + a];
            #pragma unroll
            for (int bb = 0; bb < 4; bb++) rb[bb] = sB[k2][tx * 4 + bb];
            #pragma unroll
            for (int a = 0; a < 4; a++)
                #pragma unroll
                for (int bb = 0; bb < 4; bb++)
                    acc[a][bb] = fmaf(ra[a], rb[bb], acc[a][bb]);
        }
        __syncthreads();
    }

    #pragma unroll
    for (int a = 0; a < 4; a++) {
        int row = m0 + ty * 4 + a;
        size_t rb = ((size_t)c * M + row) * N + n0 + tx * 4;
        float4 vv = make_float4(acc[a][0], acc[a][1], acc[a][2], acc[a][3]);
        if (act == 1) {
            vv.x = gelu_exact(vv.x); vv.y = gelu_exact(vv.y);
            vv.z = gelu_exact(vv.z); vv.w = gelu_exact(vv.w);
        }
        if (addsrc) {
            float4 ad = *reinterpret_cast<const float4*>(addsrc + rb);
            vv.x += ad.x; vv.y += ad.y; vv.z += ad.z; vv.w += ad.w;
        }
        *reinterpret_cast<float4*>(Out + rb) = vv;
    }
}

// ---------------------------------------------------------------------------
// RoPE + transpose: p (c,f,w) -> r (c,h,w,d) roped, v (c,h,w,d) raw.
// grid: (W/64, C*H), block 256. LDS tile (64 f x 64 w).
// ---------------------------------------------------------------------------
__global__ __launch_bounds__(256) void rope_k(
    const float* __restrict__ p, const float* __restrict__ fr,
    float* __restrict__ r, float* __restrict__ v)
{
    int ch = blockIdx.y;           // c*16 + h
    int w0 = blockIdx.x * 64;
    int c  = ch >> 4, h = ch & 15;
    __shared__ float s[64][65];    // [f_local][w_local]

    int t   = threadIdx.x;
    int wl0 = t & 63;
    int fg  = t >> 6;
    const float* pc = p + ((size_t)c * FF + h * DD) * WW;
    #pragma unroll
    for (int i = 0; i < 16; i++) {
        int fl = fg + 4 * i;
        s[fl][wl0] = pc[(size_t)fl * WW + w0 + wl0];
    }
    __syncthreads();

    int d  = t & 63;
    int wg = t >> 6;
    size_t obase = ((size_t)ch * WW + w0) * DD;
    #pragma unroll
    for (int i = 0; i < 16; i++) {
        int wl = wg + 4 * i;
        float val = s[d][wl];
        float rv;
        if (d < 32) {
            float pair = s[d ^ 1][wl];
            float th = (float)(w0 + wl) * fr[d >> 1];
            float cs = cosf(th), sn = sinf(th);
            rv = (d & 1) ? fmaf(val, cs,  pair * sn)
                         : fmaf(val, cs, -pair * sn);
        } else {
            rv = val;
        }
        size_t oi = obase + (size_t)wl * DD + d;
        r[oi] = rv;
        v[oi] = val;
    }
}

// ---------------------------------------------------------------------------
// Attention (flash-style): r is both q and k (identical rope), v raw.
// Layouts: (ch, w, d) contiguous in d. One wave per q row, 4 waves/block.
// grid: (W/4, C*H), block 256. Online softmax, scale 1/sqrt(F)=1/32.
// ---------------------------------------------------------------------------
__global__ __launch_bounds__(256) void attn_k(
    const float* __restrict__ r, const float* __restrict__ v,
    float* __restrict__ ot)
{
    int ch   = blockIdx.y;
    int wid  = threadIdx.x >> 6;
    int lane = threadIdx.x & 63;
    int q    = blockIdx.x * 4 + wid;
    const size_t base = (size_t)ch * WW * DD;

    __shared__ float sk[64][64];
    __shared__ float sv[64][64];

    float qv  = r[base + (size_t)q * DD + lane];
    float m   = -1e30f, l = 0.f, acc = 0.f;

    for (int k0 = 0; k0 < WW; k0 += 64) {
        __syncthreads();
        for (int i = threadIdx.x; i < 4096; i += 256) {
            int kr = i >> 6, d = i & 63;
            sk[kr][d] = r[base + (size_t)(k0 + kr) * DD + d];
            sv[kr][d] = v[base + (size_t)(k0 + kr) * DD + d];
        }
        __syncthreads();
        for (int k = 0; k < 64; k++) {
            float prod = qv * sk[k][lane];
            #pragma unroll
            for (int off = 32; off; off >>= 1)
                prod += __shfl_xor(prod, off, 64);
            float sc_ = prod * (1.f / 32.f);
            float mn  = fmaxf(m, sc_);
            float scale = __expf(m - mn);
            float pe    = __expf(sc_ - mn);
            acc = acc * scale + pe * sv[k][lane];
            l   = l * scale + pe;
            m   = mn;
        }
    }
    ot[base + (size_t)q * DD + lane] = acc / l;
}

// ---------------------------------------------------------------------------
// Transpose (c,h,w,d) -> (c, f=h*64+d, w). 32x32 LDS tiles.
// grid: (W/32, D/32, C*H), block 256.
// ---------------------------------------------------------------------------
__global__ __launch_bounds__(256) void trans_dw_k(
    const float* __restrict__ in, float* __restrict__ out)
{
    int ch = blockIdx.z;
    int w0 = blockIdx.x * 32;
    int d0 = blockIdx.y * 32;
    int c  = ch >> 4, h = ch & 15;
    __shared__ float s[32][33];
    int t  = threadIdx.x;
    int di = t & 31, wi = t >> 5;   // wi 0..7
    #pragma unroll
    for (int rr = 0; rr < 4; rr++)
        s[wi + 8 * rr][di] = in[((size_t)ch * WW + w0 + wi + 8 * rr) * DD + d0 + di];
    __syncthreads();
    int wi2 = t & 31, di2 = t >> 5;
    #pragma unroll
    for (int rr = 0; rr < 4; rr++)
        out[((size_t)c * FF + h * DD + d0 + di2 + 8 * rr) * WW + w0 + wi2] =
            s[wi2][di2 + 8 * rr];
}

// ---------------------------------------------------------------------------
extern "C" void kernel_launch(void* const* d_in, const int* in_sizes, int n_in,
                              void* d_out, int out_size, void* d_ws, size_t ws_size,
                              hipStream_t stream)
{
    const float* x  = (const float*)d_in[0];
    const float* g1 = (const float*)d_in[1];
    const float* b1 = (const float*)d_in[2];
    const float* wq = (const float*)d_in[3];
    const float* wo = (const float*)d_in[4];
    const float* fr = (const float*)d_in[5];
    const float* g2 = (const float*)d_in[6];
    const float* b2 = (const float*)d_in[7];
    const float* w1 = (const float*)d_in[8];
    const float* w2 = (const float*)d_in[9];
    float* out = (float*)d_out;

    const size_t SZ = (size_t)CC * FF * WW;   // 4194304
    float* ws  = (float*)d_ws;
    float* z   = ws;            // 0
    float* p   = ws + 1 * SZ;   // q-proj, later reused as o_p (transposed attn out)
    float* rr  = ws + 2 * SZ;   // roped q=k, layout (c,h,w,d)
    float* vv  = ws + 3 * SZ;   // v, layout (c,h,w,d)
    float* ot  = ws + 4 * SZ;   // attention out (c,h,w,d)
    float* x2  = ws + 5 * SZ;   // residual 1 result
    float* h1  = ws + 6 * SZ;   // MLP hidden (c, 4096, 512) = 4*SZ floats

    dim3 blk(256);

    // 1. z = frame_norm(x, g1, b1)
    frame_norm_k<<<dim3(WW / 64, CC), blk, 0, stream>>>(x, g1, b1, z);

    // 2. p = mc_linear(z, w_q)
    gemm_ck<<<dim3(WW / 64, FF / 64, CC), blk, 0, stream>>>(
        wq, z, p, nullptr, FF, FF, WW, 0);

    // 3. rope: p -> rr (roped), vv (raw) in (c,h,w,d)
    rope_k<<<dim3(WW / 64, CC * HH), blk, 0, stream>>>(p, fr, rr, vv);

    // 4. attention -> ot (c,h,w,d)
    attn_k<<<dim3(WW / 4, CC * HH), blk, 0, stream>>>(rr, vv, ot);

    // 5. transpose ot -> p (now o in (c,f,w))
    trans_dw_k<<<dim3(WW / 32, DD / 32, CC * HH), blk, 0, stream>>>(ot, p);

    // 6. x2 = x + mc_linear(o, w_o)
    gemm_ck<<<dim3(WW / 64, FF / 64, CC), blk, 0, stream>>>(
        wo, p, x2, x, FF, FF, WW, 0);

    // 7. z = frame_norm(x2, g2, b2)
    frame_norm_k<<<dim3(WW / 64, CC), blk, 0, stream>>>(x2, g2, b2, z);

    // 8. h1 = gelu(mc_linear(z, w1))
    gemm_ck<<<dim3(WW / 64, FE / 64, CC), blk, 0, stream>>>(
        w1, z, h1, nullptr, FE, FF, WW, 1);

    // 9. out = x2 + mc_linear(h1, w2)
    gemm_ck<<<dim3(WW / 64, FF / 64, CC), blk, 0, stream>>>(
        w2, h1, out, x2, FF, FE, WW, 0);
}

// Round 2
// 844.476 us; speedup vs baseline: 4.7337x; 4.7337x over previous
//
#include <hip/hip_runtime.h>
#include <math.h>

#define CC 8
#define FF 1024
#define WW 512
#define HH 16
#define DD 64
#define FE 4096
#define EPS_ 1e-5f

typedef __attribute__((ext_vector_type(8))) short bf16x8;
typedef __attribute__((ext_vector_type(4))) float f32x4;

static __device__ __forceinline__ unsigned short f2bf(float f) {
    unsigned u = __float_as_uint(f);
    u += 0x7fffu + ((u >> 16) & 1u);          // round-to-nearest-even
    return (unsigned short)(u >> 16);
}
static __device__ __forceinline__ float bf2f(unsigned short h) {
    return __uint_as_float(((unsigned)h) << 16);
}
static __device__ __forceinline__ float gelu_exact(float v) {
    return 0.5f * v * (1.0f + erff(v * 0.70710678118654752f));
}

// ---------------------------------------------------------------------------
// frame_norm over F per (c,w) column, x (c,f,w) fp32 -> zt (c,w,f) bf16
// grid (W/64, C), block 256 = 64 w-lanes x 4 wave-groups
// ---------------------------------------------------------------------------
__global__ __launch_bounds__(256) void frame_norm_t_k(
    const float* __restrict__ x, const float* __restrict__ g,
    const float* __restrict__ b, unsigned short* __restrict__ zt)
{
    int c  = blockIdx.y;
    int w0 = blockIdx.x * 64;
    int t  = threadIdx.x;
    int wl = t & 63;
    int fg = t >> 6;               // wave index, 0..3
    const float* xc = x + (size_t)c * FF * WW;

    float sum = 0.f, sq = 0.f;
    for (int f = fg; f < FF; f += 4) {
        float v = xc[(size_t)f * WW + w0 + wl];
        sum += v; sq += v * v;
    }
    __shared__ float ssum[4][64], ssq[4][64], smu[64], srv[64];
    ssum[fg][wl] = sum; ssq[fg][wl] = sq;
    __syncthreads();
    if (fg == 0) {
        float s = 0.f, q = 0.f;
        #pragma unroll
        for (int j = 0; j < 4; j++) { s += ssum[j][wl]; q += ssq[j][wl]; }
        float mu  = s * (1.f / FF);
        float var = q * (1.f / FF) - mu * mu;
        smu[wl] = mu;
        srv[wl] = rsqrtf(var + EPS_);
    }
    __syncthreads();
    float mu = smu[wl], rv = srv[wl];

    __shared__ float sT[64][65];
    unsigned short* ztc = zt + (size_t)c * WW * FF;
    for (int f0 = 0; f0 < FF; f0 += 64) {
        #pragma unroll
        for (int i = 0; i < 16; i++) {
            int fl = fg * 16 + i;
            int f  = f0 + fl;
            float v = xc[(size_t)f * WW + w0 + wl];
            sT[fl][wl] = (v - mu) * rv * g[f] + b[f];
        }
        __syncthreads();
        #pragma unroll
        for (int i = 0; i < 16; i++) {
            int wr = fg * 16 + i;                 // w row (wave-uniform)
            ztc[(size_t)(w0 + wr) * FF + f0 + wl] = f2bf(sT[wl][wr]);
        }
        __syncthreads();
    }
}

// ---------------------------------------------------------------------------
// bf16 MFMA GEMM: Out[c,m,n] = sum_k A[c,m,k] * Bt[c,n,k]
// A fp32 (C,M,K) k-contig (weights, converted in staging);
// Bt bf16 (C,512,K) k-contig (activations, pre-transposed).
// 128x128 tile, 4 waves (2x2), 64x64/wave, 4x4 mfma_f32_16x16x32_bf16 frags.
// mode 0: write bf16 TRANSPOSED (c,n,m); 1: fp32 (c,m,n) + Add;
// mode 2: GELU then bf16 transposed.
// ---------------------------------------------------------------------------
__global__ __launch_bounds__(256) void gemm_bt_k(
    const float* __restrict__ A, const unsigned short* __restrict__ Bt,
    float* __restrict__ Outf, unsigned short* __restrict__ Outb,
    const float* __restrict__ Add, int M, int K, int mode)
{
    int c  = blockIdx.z;
    int m0 = blockIdx.y * 128;
    int n0 = blockIdx.x * 128;
    const float*          Ac = A  + (size_t)c * M * K;
    const unsigned short* Bc = Bt + (size_t)c * 512 * K;

    // pitch 56 elems = 112 B: 16B-aligned b128 reads, bank-spread (112%128!=0)
    __shared__ unsigned short sA[128 * 56];
    __shared__ unsigned short sB[128 * 56];

    int t    = threadIdx.x;
    int lane = t & 63;
    int wid  = t >> 6;
    int wm   = (wid >> 1) * 64, wn = (wid & 1) * 64;
    int frl  = lane & 15, fgr = lane >> 4;

    f32x4 acc[4][4];
    #pragma unroll
    for (int i = 0; i < 4; i++)
        #pragma unroll
        for (int j = 0; j < 4; j++) acc[i][j] = (f32x4){0.f, 0.f, 0.f, 0.f};

    int arow = t >> 3, acol = (t & 7) * 4;   // A: 4 rounds of 32 rows
    int brow = t >> 2, bcol = (t & 3) * 8;   // B: 2 rounds of 64 rows

    for (int k0 = 0; k0 < K; k0 += 32) {
        #pragma unroll
        for (int r = 0; r < 4; r++) {
            int row = r * 32 + arow;
            float4 v = *reinterpret_cast<const float4*>(
                Ac + (size_t)(m0 + row) * K + k0 + acol);
            ushort4 h;
            h.x = f2bf(v.x); h.y = f2bf(v.y); h.z = f2bf(v.z); h.w = f2bf(v.w);
            *reinterpret_cast<ushort4*>(&sA[row * 56 + acol]) = h;
        }
        #pragma unroll
        for (int r = 0; r < 2; r++) {
            int row = r * 64 + brow;
            bf16x8 v = *reinterpret_cast<const bf16x8*>(
                Bc + (size_t)(n0 + row) * K + k0 + bcol);
            *reinterpret_cast<bf16x8*>(&sB[row * 56 + bcol]) = v;
        }
        __syncthreads();

        bf16x8 af[4], bfv[4];
        #pragma unroll
        for (int mi = 0; mi < 4; mi++)
            af[mi] = *reinterpret_cast<const bf16x8*>(
                &sA[(wm + mi * 16 + frl) * 56 + fgr * 8]);
        #pragma unroll
        for (int ni = 0; ni < 4; ni++)
            bfv[ni] = *reinterpret_cast<const bf16x8*>(
                &sB[(wn + ni * 16 + frl) * 56 + fgr * 8]);
        #pragma unroll
        for (int mi = 0; mi < 4; mi++)
            #pragma unroll
            for (int ni = 0; ni < 4; ni++)
                acc[mi][ni] = __builtin_amdgcn_mfma_f32_16x16x32_bf16(
                    af[mi], bfv[ni], acc[mi][ni], 0, 0, 0);
        __syncthreads();
    }

    // C/D layout: col = lane&15, row = (lane>>4)*4 + reg  [measured m89/m91]
    if (mode == 1) {
        #pragma unroll
        for (int mi = 0; mi < 4; mi++)
            #pragma unroll
            for (int ni = 0; ni < 4; ni++) {
                int mrow = m0 + wm + mi * 16 + fgr * 4;
                int ncol = n0 + wn + ni * 16 + frl;
                #pragma unroll
                for (int r = 0; r < 4; r++) {
                    size_t o = ((size_t)c * M + mrow + r) * 512 + ncol;
                    Outf[o] = acc[mi][ni][r] + Add[o];
                }
            }
    } else {
        bool gel = (mode == 2);
        #pragma unroll
        for (int mi = 0; mi < 4; mi++)
            #pragma unroll
            for (int ni = 0; ni < 4; ni++) {
                f32x4 v = acc[mi][ni];
                if (gel) {
                    v[0] = gelu_exact(v[0]); v[1] = gelu_exact(v[1]);
                    v[2] = gelu_exact(v[2]); v[3] = gelu_exact(v[3]);
                }
                int mrow = m0 + wm + mi * 16 + fgr * 4;
                int ncol = n0 + wn + ni * 16 + frl;
                ushort4 h;
                h.x = f2bf(v[0]); h.y = f2bf(v[1]);
                h.z = f2bf(v[2]); h.w = f2bf(v[3]);
                *reinterpret_cast<ushort4*>(
                    &Outb[((size_t)c * 512 + ncol) * M + mrow]) = h;
            }
    }
}

// ---------------------------------------------------------------------------
// Attention, tiled fp32 VALU, RoPE fused into staging. q = k = rope(t).
// pt (c,w,f=h*64+d) bf16. Block: one head, 64 q-rows; k-tiles of 64.
// Thread (qg,kg) = (t>>4, t&15) owns 4x4 scores / 4x4 output dims.
// grid (W/64, C*H), block 256.
// ---------------------------------------------------------------------------
__global__ __launch_bounds__(256) void attn_k(
    const unsigned short* __restrict__ pt, const float* __restrict__ fr,
    unsigned short* __restrict__ ot)
{
    int ch = blockIdx.y;
    int c  = ch >> 4, h = ch & 15;
    int q0 = blockIdx.x * 64;
    int t  = threadIdx.x;
    int d  = t & 63, rg = t >> 6;
    const unsigned short* base = pt + (size_t)c * WW * FF + h * DD;

    __shared__ float Qs[64][65], Ks[64][65], Vs[64][65], Ps[64][65];

    float myfreq = (d < 32) ? fr[d >> 1] : 0.f;

    #pragma unroll
    for (int i = 0; i < 16; i++) {
        int r = rg * 16 + i;
        int w = q0 + r;
        float val  = bf2f(base[(size_t)w * FF + d]);
        float pair = __shfl_xor(val, 1, 64);
        float rv = val;
        if (d < 32) {
            float sn, cs;
            __sincosf((float)w * myfreq, &sn, &cs);
            rv = (d & 1) ? fmaf(val, cs, pair * sn) : fmaf(val, cs, -pair * sn);
        }
        Qs[r][d] = rv;
    }

    int qg = t >> 4;   // 0..15
    int kg = t & 15;
    float m_[4], l_[4], oacc[4][4];
    #pragma unroll
    for (int i = 0; i < 4; i++) {
        m_[i] = -1e30f; l_[i] = 0.f;
        #pragma unroll
        for (int j = 0; j < 4; j++) oacc[i][j] = 0.f;
    }

    for (int k0 = 0; k0 < WW; k0 += 64) {
        __syncthreads();
        #pragma unroll
        for (int i = 0; i < 16; i++) {
            int r = rg * 16 + i;
            int w = k0 + r;
            float val  = bf2f(base[(size_t)w * FF + d]);
            float pair = __shfl_xor(val, 1, 64);
            float rv = val;
            if (d < 32) {
                float sn, cs;
                __sincosf((float)w * myfreq, &sn, &cs);
                rv = (d & 1) ? fmaf(val, cs, pair * sn) : fmaf(val, cs, -pair * sn);
            }
            Ks[r][d] = rv;
            Vs[r][d] = val;
        }
        __syncthreads();

        float s_[4][4];
        #pragma unroll
        for (int i = 0; i < 4; i++)
            #pragma unroll
            for (int j = 0; j < 4; j++) s_[i][j] = 0.f;

        #pragma unroll 8
        for (int dd = 0; dd < 64; dd++) {
            float ra[4], rb[4];
            #pragma unroll
            for (int i = 0; i < 4; i++) ra[i] = Qs[qg * 4 + i][dd];
            #pragma unroll
            for (int j = 0; j < 4; j++) rb[j] = Ks[kg * 4 + j][dd];
            #pragma unroll
            for (int i = 0; i < 4; i++)
                #pragma unroll
                for (int j = 0; j < 4; j++)
                    s_[i][j] = fmaf(ra[i], rb[j], s_[i][j]);
        }
        #pragma unroll
        for (int i = 0; i < 4; i++)
            #pragma unroll
            for (int j = 0; j < 4; j++) s_[i][j] *= (1.f / 32.f);

        #pragma unroll
        for (int i = 0; i < 4; i++) {
            float mx = fmaxf(fmaxf(s_[i][0], s_[i][1]), fmaxf(s_[i][2], s_[i][3]));
            mx = fmaxf(mx, __shfl_xor(mx, 1, 64));
            mx = fmaxf(mx, __shfl_xor(mx, 2, 64));
            mx = fmaxf(mx, __shfl_xor(mx, 4, 64));
            mx = fmaxf(mx, __shfl_xor(mx, 8, 64));
            float mn    = fmaxf(m_[i], mx);
            float scale = __expf(m_[i] - mn);
            float rs = 0.f;
            #pragma unroll
            for (int j = 0; j < 4; j++) {
                float p = __expf(s_[i][j] - mn);
                Ps[qg * 4 + i][kg * 4 + j] = p;
                rs += p;
            }
            rs += __shfl_xor(rs, 1, 64);
            rs += __shfl_xor(rs, 2, 64);
            rs += __shfl_xor(rs, 4, 64);
            rs += __shfl_xor(rs, 8, 64);
            l_[i] = l_[i] * scale + rs;
            m_[i] = mn;
            #pragma unroll
            for (int j = 0; j < 4; j++) oacc[i][j] *= scale;
        }
        __syncthreads();

        #pragma unroll 8
        for (int kk = 0; kk < 64; kk++) {
            float ra[4], rb[4];
            #pragma unroll
            for (int i = 0; i < 4; i++) ra[i] = Ps[qg * 4 + i][kk];
            #pragma unroll
            for (int j = 0; j < 4; j++) rb[j] = Vs[kk][kg * 4 + j];
            #pragma unroll
            for (int i = 0; i < 4; i++)
                #pragma unroll
                for (int j = 0; j < 4; j++)
                    oacc[i][j] = fmaf(ra[i], rb[j], oacc[i][j]);
        }
    }

    unsigned short* ob = ot + (size_t)c * WW * FF + h * DD;
    #pragma unroll
    for (int i = 0; i < 4; i++) {
        float inv = 1.f / l_[i];
        int w = q0 + qg * 4 + i;
        ushort4 hv;
        hv.x = f2bf(oacc[i][0] * inv); hv.y = f2bf(oacc[i][1] * inv);
        hv.z = f2bf(oacc[i][2] * inv); hv.w = f2bf(oacc[i][3] * inv);
        *reinterpret_cast<ushort4*>(&ob[(size_t)w * FF + kg * 4]) = hv;
    }
}

// ---------------------------------------------------------------------------
extern "C" void kernel_launch(void* const* d_in, const int* in_sizes, int n_in,
                              void* d_out, int out_size, void* d_ws, size_t ws_size,
                              hipStream_t stream)
{
    const float* x  = (const float*)d_in[0];
    const float* g1 = (const float*)d_in[1];
    const float* b1 = (const float*)d_in[2];
    const float* wq = (const float*)d_in[3];
    const float* wo = (const float*)d_in[4];
    const float* fr = (const float*)d_in[5];
    const float* g2 = (const float*)d_in[6];
    const float* b2 = (const float*)d_in[7];
    const float* w1 = (const float*)d_in[8];
    const float* w2 = (const float*)d_in[9];

    const size_t SZ = (size_t)CC * FF * WW;       // 4194304 elems
    char* wsb = (char*)d_ws;
    unsigned short* zt  = (unsigned short*)(wsb);            // bf16 (c,w,f)
    unsigned short* ptb = (unsigned short*)(wsb + 2 * SZ);   // bf16 (c,w,f)
    unsigned short* otb = (unsigned short*)(wsb + 4 * SZ);   // bf16 (c,w,f)
    float*          x2  = (float*)        (wsb + 6 * SZ);    // fp32 (c,f,w)
    unsigned short* h1t = (unsigned short*)(wsb + 10 * SZ);  // bf16 (c,w,4096)

    dim3 blk(256);

    // 1. zt = frame_norm(x)^T (bf16)
    frame_norm_t_k<<<dim3(WW / 64, CC), blk, 0, stream>>>(x, g1, b1, zt);
    // 2. pt = (wq . z)^T (bf16, (c,w,f))
    gemm_bt_k<<<dim3(4, 8, CC), blk, 0, stream>>>(wq, zt, nullptr, ptb, nullptr, FF, FF, 0);
    // 3. attention (rope fused) -> otb (c,w,f) bf16
    attn_k<<<dim3(WW / 64, CC * HH), blk, 0, stream>>>(ptb, fr, otb);
    // 4. x2 = x + wo . o   (fp32 (c,f,w))
    gemm_bt_k<<<dim3(4, 8, CC), blk, 0, stream>>>(wo, otb, x2, nullptr, x, FF, FF, 1);
    // 5. zt = frame_norm(x2)^T
    frame_norm_t_k<<<dim3(WW / 64, CC), blk, 0, stream>>>(x2, g2, b2, zt);
    // 6. h1t = gelu(w1 . z2)^T  (bf16 (c,w,4096))
    gemm_bt_k<<<dim3(4, 32, CC), blk, 0, stream>>>(w1, zt, nullptr, h1t, nullptr, FE, FF, 2);
    // 7. out = x2 + w2 . h1  (fp32 (c,f,w))
    gemm_bt_k<<<dim3(4, 8, CC), blk, 0, stream>>>(w2, h1t, (float*)d_out, nullptr, x2, FF, FE, 1);
}

// Round 3
// 624.442 us; speedup vs baseline: 6.4017x; 1.3524x over previous
//
#include <hip/hip_runtime.h>
#include <math.h>

#define CC 8
#define FF 1024
#define WW 512
#define HH 16
#define DD 64
#define FE 4096
#define EPS_ 1e-5f

typedef __attribute__((ext_vector_type(8))) short bf16x8;
typedef __attribute__((ext_vector_type(4))) float f32x4;

static __device__ __forceinline__ unsigned short f2bf(float f) {
    unsigned u = __float_as_uint(f);
    u += 0x7fffu + ((u >> 16) & 1u);          // round-to-nearest-even
    return (unsigned short)(u >> 16);
}
static __device__ __forceinline__ float bf2f(unsigned short h) {
    return __uint_as_float(((unsigned)h) << 16);
}
static __device__ __forceinline__ float gelu_exact(float v) {
    return 0.5f * v * (1.0f + erff(v * 0.70710678118654752f));
}

typedef const __attribute__((address_space(1))) unsigned int* gas_p;
typedef __attribute__((address_space(3))) unsigned int* las_p;
static __device__ __forceinline__ void gload_lds16(const void* g, void* l) {
    __builtin_amdgcn_global_load_lds((gas_p)g, (las_p)l, 16, 0, 0);
}

// ---------------------------------------------------------------------------
// frame_norm over F per (c,w) column, x (c,f,w) fp32 -> zt (c,w,f) bf16
// ---------------------------------------------------------------------------
__global__ __launch_bounds__(256) void frame_norm_t_k(
    const float* __restrict__ x, const float* __restrict__ g,
    const float* __restrict__ b, unsigned short* __restrict__ zt)
{
    int c  = blockIdx.y;
    int w0 = blockIdx.x * 64;
    int t  = threadIdx.x;
    int wl = t & 63;
    int fg = t >> 6;
    const float* xc = x + (size_t)c * FF * WW;

    float sum = 0.f, sq = 0.f;
    for (int f = fg; f < FF; f += 4) {
        float v = xc[(size_t)f * WW + w0 + wl];
        sum += v; sq += v * v;
    }
    __shared__ float ssum[4][64], ssq[4][64], smu[64], srv[64];
    ssum[fg][wl] = sum; ssq[fg][wl] = sq;
    __syncthreads();
    if (fg == 0) {
        float s = 0.f, q = 0.f;
        #pragma unroll
        for (int j = 0; j < 4; j++) { s += ssum[j][wl]; q += ssq[j][wl]; }
        float mu  = s * (1.f / FF);
        float var = q * (1.f / FF) - mu * mu;
        smu[wl] = mu;
        srv[wl] = rsqrtf(var + EPS_);
    }
    __syncthreads();
    float mu = smu[wl], rv = srv[wl];

    __shared__ float sT[64][65];
    unsigned short* ztc = zt + (size_t)c * WW * FF;
    for (int f0 = 0; f0 < FF; f0 += 64) {
        #pragma unroll
        for (int i = 0; i < 16; i++) {
            int fl = fg * 16 + i;
            int f  = f0 + fl;
            float v = xc[(size_t)f * WW + w0 + wl];
            sT[fl][wl] = (v - mu) * rv * g[f] + b[f];
        }
        __syncthreads();
        #pragma unroll
        for (int i = 0; i < 16; i++) {
            int wr = fg * 16 + i;
            ztc[(size_t)(w0 + wr) * FF + f0 + wl] = f2bf(sT[wl][wr]);
        }
        __syncthreads();
    }
}

// ---------------------------------------------------------------------------
// bf16 MFMA GEMM: Out[c,m,n] = sum_k A[c,m,k] * Bt[c,n,k]
// A fp32 (C,M,K) (weights, converted in staging); Bt bf16 (C,512,K).
// 128x128 tile, 4 waves, B staged via global_load_lds (linear [128][32]).
// mode 0: bf16 transposed out; 1: fp32 (c,m,n)+Add; 2: GELU bf16 transposed.
// ---------------------------------------------------------------------------
__global__ __launch_bounds__(256) void gemm_bt_k(
    const float* __restrict__ A, const unsigned short* __restrict__ Bt,
    float* __restrict__ Outf, unsigned short* __restrict__ Outb,
    const float* __restrict__ Add, int M, int K, int mode)
{
    int c  = blockIdx.z;
    int m0 = blockIdx.y * 128;
    int n0 = blockIdx.x * 128;
    const float*          Ac = A  + (size_t)c * M * K;
    const unsigned short* Bc = Bt + (size_t)c * 512 * K;

    __shared__ unsigned short sA[128 * 56];   // pitch 56, bank-spread
    __shared__ unsigned short sB[128 * 32];   // linear for global_load_lds

    int t    = threadIdx.x;
    int lane = t & 63;
    int wid  = t >> 6;
    int wm   = (wid >> 1) * 64, wn = (wid & 1) * 64;
    int frl  = lane & 15, fgr = lane >> 4;

    f32x4 acc[4][4];
    #pragma unroll
    for (int i = 0; i < 4; i++)
        #pragma unroll
        for (int j = 0; j < 4; j++) acc[i][j] = (f32x4){0.f, 0.f, 0.f, 0.f};

    int arow = t >> 3, acol = (t & 7) * 4;

    for (int k0 = 0; k0 < K; k0 += 32) {
        // B: async global->LDS, 16B/lane, wave-contiguous dest
        #pragma unroll
        for (int r = 0; r < 2; r++) {
            const unsigned short* gs = Bc +
                (size_t)(n0 + r * 64 + wid * 16 + (lane >> 2)) * K + k0 + (lane & 3) * 8;
            gload_lds16(gs, &sB[(r * 64 + wid * 16) * 32]);
        }
        // A: fp32 -> bf16 reg staging
        #pragma unroll
        for (int r = 0; r < 4; r++) {
            int row = r * 32 + arow;
            float4 v = *reinterpret_cast<const float4*>(
                Ac + (size_t)(m0 + row) * K + k0 + acol);
            ushort4 h;
            h.x = f2bf(v.x); h.y = f2bf(v.y); h.z = f2bf(v.z); h.w = f2bf(v.w);
            *reinterpret_cast<ushort4*>(&sA[row * 56 + acol]) = h;
        }
        __syncthreads();

        bf16x8 af[4], bfv[4];
        #pragma unroll
        for (int mi = 0; mi < 4; mi++)
            af[mi] = *reinterpret_cast<const bf16x8*>(
                &sA[(wm + mi * 16 + frl) * 56 + fgr * 8]);
        #pragma unroll
        for (int ni = 0; ni < 4; ni++)
            bfv[ni] = *reinterpret_cast<const bf16x8*>(
                &sB[(wn + ni * 16 + frl) * 32 + fgr * 8]);
        #pragma unroll
        for (int mi = 0; mi < 4; mi++)
            #pragma unroll
            for (int ni = 0; ni < 4; ni++)
                acc[mi][ni] = __builtin_amdgcn_mfma_f32_16x16x32_bf16(
                    af[mi], bfv[ni], acc[mi][ni], 0, 0, 0);
        __syncthreads();
    }

    if (mode == 1) {
        #pragma unroll
        for (int mi = 0; mi < 4; mi++)
            #pragma unroll
            for (int ni = 0; ni < 4; ni++) {
                int mrow = m0 + wm + mi * 16 + fgr * 4;
                int ncol = n0 + wn + ni * 16 + frl;
                #pragma unroll
                for (int r = 0; r < 4; r++) {
                    size_t o = ((size_t)c * M + mrow + r) * 512 + ncol;
                    Outf[o] = acc[mi][ni][r] + Add[o];
                }
            }
    } else {
        bool gel = (mode == 2);
        #pragma unroll
        for (int mi = 0; mi < 4; mi++)
            #pragma unroll
            for (int ni = 0; ni < 4; ni++) {
                f32x4 v = acc[mi][ni];
                if (gel) {
                    v[0] = gelu_exact(v[0]); v[1] = gelu_exact(v[1]);
                    v[2] = gelu_exact(v[2]); v[3] = gelu_exact(v[3]);
                }
                int mrow = m0 + wm + mi * 16 + fgr * 4;
                int ncol = n0 + wn + ni * 16 + frl;
                ushort4 h;
                h.x = f2bf(v[0]); h.y = f2bf(v[1]);
                h.z = f2bf(v[2]); h.w = f2bf(v[3]);
                *reinterpret_cast<ushort4*>(
                    &Outb[((size_t)c * 512 + ncol) * M + mrow]) = h;
            }
    }
}

// ---------------------------------------------------------------------------
// MFMA flash attention. pt (c,w,f=h*64+d) bf16, rope fused into staging.
// Block = (c,h) x 64-q tile; 4 waves x 16 q rows. K-tiles of 64.
// S/PV via mfma_f32_16x16x32_bf16 using the GEMM's verified frag convention:
// operands: row = lane&15 of k-contig LDS tile; C/D: row=(lane>>4)*4+reg,
// col=lane&15.
// ---------------------------------------------------------------------------
__global__ __launch_bounds__(256) void attn_mfma_k(
    const unsigned short* __restrict__ pt, const float* __restrict__ fr,
    unsigned short* __restrict__ ot)
{
    int ch = blockIdx.y;
    int c  = ch >> 4, h = ch & 15;
    int q0 = blockIdx.x * 64;
    int t  = threadIdx.x;
    int lane = t & 63;
    int wid  = t >> 6;
    int frl  = lane & 15, fgr = lane >> 4;

    const unsigned short* base = pt + (size_t)c * WW * FF + h * DD;

    __shared__ unsigned short Qs[64 * 72];            // [q][d] roped
    __shared__ unsigned short Ks[64 * 72];            // [k][d] roped
    __shared__ unsigned short Vt[64 * 72];            // [d][k] transposed
    __shared__ unsigned short Ps[4 * 16 * 72];        // per-wave [q_loc][k]

    // ---- stage Q (roped, once) ----
    {
        int kr = t >> 3, d0 = (t & 7) * 8;
        #pragma unroll
        for (int r = 0; r < 2; r++) {
            int row = kr + r * 32;
            int w   = q0 + row;
            bf16x8 v = *reinterpret_cast<const bf16x8*>(&base[(size_t)w * FF + d0]);
            bf16x8 o;
            if (d0 < 32) {
                #pragma unroll
                for (int j = 0; j < 8; j += 2) {
                    float x1 = bf2f((unsigned short)v[j]);
                    float x2 = bf2f((unsigned short)v[j + 1]);
                    float sn, cs;
                    __sincosf((float)w * fr[(d0 + j) >> 1], &sn, &cs);
                    o[j]     = (short)f2bf(x1 * cs - x2 * sn);
                    o[j + 1] = (short)f2bf(x2 * cs + x1 * sn);
                }
            } else o = v;
            *reinterpret_cast<bf16x8*>(&Qs[row * 72 + d0]) = o;
        }
    }

    f32x4 oacc[4];
    float m_[4], l_[4];
    #pragma unroll
    for (int i = 0; i < 4; i++) {
        oacc[i] = (f32x4){0.f, 0.f, 0.f, 0.f};
        m_[i] = -1e30f; l_[i] = 0.f;
    }
    unsigned short* myP = &Ps[wid * 16 * 72];
    int wq0 = wid * 16;

    for (int k0 = 0; k0 < WW; k0 += 64) {
        __syncthreads();
        // ---- stage K (roped) ----
        {
            int kr = t >> 3, d0 = (t & 7) * 8;
            #pragma unroll
            for (int r = 0; r < 2; r++) {
                int row = kr + r * 32;
                int w   = k0 + row;
                bf16x8 v = *reinterpret_cast<const bf16x8*>(&base[(size_t)w * FF + d0]);
                bf16x8 o;
                if (d0 < 32) {
                    #pragma unroll
                    for (int j = 0; j < 8; j += 2) {
                        float x1 = bf2f((unsigned short)v[j]);
                        float x2 = bf2f((unsigned short)v[j + 1]);
                        float sn, cs;
                        __sincosf((float)w * fr[(d0 + j) >> 1], &sn, &cs);
                        o[j]     = (short)f2bf(x1 * cs - x2 * sn);
                        o[j + 1] = (short)f2bf(x2 * cs + x1 * sn);
                    }
                } else o = v;
                *reinterpret_cast<bf16x8*>(&Ks[row * 72 + d0]) = o;
            }
        }
        // ---- stage V transposed: Vt[d][k], 8 k-consecutive per thread ----
        {
            int d  = t & 63;
            int kb = (t >> 6) * 8;
            #pragma unroll
            for (int r = 0; r < 2; r++) {
                int kk = kb + r * 32;
                bf16x8 o;
                #pragma unroll
                for (int j = 0; j < 8; j++)
                    o[j] = (short)base[(size_t)(k0 + kk + j) * FF + d];
                *reinterpret_cast<bf16x8*>(&Vt[d * 72 + kk]) = o;
            }
        }
        __syncthreads();

        // ---- S = Q K^T for this wave's 16 q rows ----
        f32x4 s[4];
        #pragma unroll
        for (int nt = 0; nt < 4; nt++) s[nt] = (f32x4){0.f, 0.f, 0.f, 0.f};
        bf16x8 aq0 = *reinterpret_cast<const bf16x8*>(&Qs[(wq0 + frl) * 72 + fgr * 8]);
        bf16x8 aq1 = *reinterpret_cast<const bf16x8*>(&Qs[(wq0 + frl) * 72 + 32 + fgr * 8]);
        #pragma unroll
        for (int nt = 0; nt < 4; nt++) {
            bf16x8 b0 = *reinterpret_cast<const bf16x8*>(&Ks[(nt * 16 + frl) * 72 + fgr * 8]);
            bf16x8 b1 = *reinterpret_cast<const bf16x8*>(&Ks[(nt * 16 + frl) * 72 + 32 + fgr * 8]);
            s[nt] = __builtin_amdgcn_mfma_f32_16x16x32_bf16(aq0, b0, s[nt], 0, 0, 0);
            s[nt] = __builtin_amdgcn_mfma_f32_16x16x32_bf16(aq1, b1, s[nt], 0, 0, 0);
        }

        // ---- online softmax (row r lives on 16 frl lanes) ----
        #pragma unroll
        for (int r = 0; r < 4; r++) {
            float sv[4];
            #pragma unroll
            for (int nt = 0; nt < 4; nt++) sv[nt] = s[nt][r] * (1.f / 32.f);
            float mx = fmaxf(fmaxf(sv[0], sv[1]), fmaxf(sv[2], sv[3]));
            mx = fmaxf(mx, __shfl_xor(mx, 1, 64));
            mx = fmaxf(mx, __shfl_xor(mx, 2, 64));
            mx = fmaxf(mx, __shfl_xor(mx, 4, 64));
            mx = fmaxf(mx, __shfl_xor(mx, 8, 64));
            float mn    = fmaxf(m_[r], mx);
            float scale = __expf(m_[r] - mn);
            float rs = 0.f;
            #pragma unroll
            for (int nt = 0; nt < 4; nt++) {
                float p = __expf(sv[nt] - mn);
                myP[(fgr * 4 + r) * 72 + nt * 16 + frl] = f2bf(p);
                rs += p;
            }
            rs += __shfl_xor(rs, 1, 64);
            rs += __shfl_xor(rs, 2, 64);
            rs += __shfl_xor(rs, 4, 64);
            rs += __shfl_xor(rs, 8, 64);
            l_[r] = l_[r] * scale + rs;
            m_[r] = mn;
            #pragma unroll
            for (int dt = 0; dt < 4; dt++) oacc[dt][r] *= scale;
        }

        // ---- O += P V ----
        bf16x8 ap0 = *reinterpret_cast<const bf16x8*>(&myP[frl * 72 + fgr * 8]);
        bf16x8 ap1 = *reinterpret_cast<const bf16x8*>(&myP[frl * 72 + 32 + fgr * 8]);
        #pragma unroll
        for (int dt = 0; dt < 4; dt++) {
            bf16x8 b0 = *reinterpret_cast<const bf16x8*>(&Vt[(dt * 16 + frl) * 72 + fgr * 8]);
            bf16x8 b1 = *reinterpret_cast<const bf16x8*>(&Vt[(dt * 16 + frl) * 72 + 32 + fgr * 8]);
            oacc[dt] = __builtin_amdgcn_mfma_f32_16x16x32_bf16(ap0, b0, oacc[dt], 0, 0, 0);
            oacc[dt] = __builtin_amdgcn_mfma_f32_16x16x32_bf16(ap1, b1, oacc[dt], 0, 0, 0);
        }
    }

    // ---- write O (c,w,f) bf16 ----
    unsigned short* ob = ot + (size_t)c * WW * FF + h * DD;
    #pragma unroll
    for (int r = 0; r < 4; r++) {
        float inv = 1.f / l_[r];
        int w = q0 + wq0 + fgr * 4 + r;
        #pragma unroll
        for (int dt = 0; dt < 4; dt++)
            ob[(size_t)w * FF + dt * 16 + frl] = f2bf(oacc[dt][r] * inv);
    }
}

// ---------------------------------------------------------------------------
extern "C" void kernel_launch(void* const* d_in, const int* in_sizes, int n_in,
                              void* d_out, int out_size, void* d_ws, size_t ws_size,
                              hipStream_t stream)
{
    const float* x  = (const float*)d_in[0];
    const float* g1 = (const float*)d_in[1];
    const float* b1 = (const float*)d_in[2];
    const float* wq = (const float*)d_in[3];
    const float* wo = (const float*)d_in[4];
    const float* fr = (const float*)d_in[5];
    const float* g2 = (const float*)d_in[6];
    const float* b2 = (const float*)d_in[7];
    const float* w1 = (const float*)d_in[8];
    const float* w2 = (const float*)d_in[9];

    const size_t SZ = (size_t)CC * FF * WW;
    char* wsb = (char*)d_ws;
    unsigned short* zt  = (unsigned short*)(wsb);            // bf16 (c,w,f)
    unsigned short* ptb = (unsigned short*)(wsb + 2 * SZ);   // bf16 (c,w,f)
    unsigned short* otb = (unsigned short*)(wsb + 4 * SZ);   // bf16 (c,w,f)
    float*          x2  = (float*)        (wsb + 6 * SZ);    // fp32 (c,f,w)
    unsigned short* h1t = (unsigned short*)(wsb + 10 * SZ);  // bf16 (c,w,4096)

    dim3 blk(256);

    frame_norm_t_k<<<dim3(WW / 64, CC), blk, 0, stream>>>(x, g1, b1, zt);
    gemm_bt_k<<<dim3(4, 8, CC), blk, 0, stream>>>(wq, zt, nullptr, ptb, nullptr, FF, FF, 0);
    attn_mfma_k<<<dim3(WW / 64, CC * HH), blk, 0, stream>>>(ptb, fr, otb);
    gemm_bt_k<<<dim3(4, 8, CC), blk, 0, stream>>>(wo, otb, x2, nullptr, x, FF, FF, 1);
    frame_norm_t_k<<<dim3(WW / 64, CC), blk, 0, stream>>>(x2, g2, b2, zt);
    gemm_bt_k<<<dim3(4, 32, CC), blk, 0, stream>>>(w1, zt, nullptr, h1t, nullptr, FE, FF, 2);
    gemm_bt_k<<<dim3(4, 8, CC), blk, 0, stream>>>(w2, h1t, (float*)d_out, nullptr, x2, FF, FE, 1);
}

// Round 4
// 578.534 us; speedup vs baseline: 6.9096x; 1.0794x over previous
//
#include <hip/hip_runtime.h>
#include <math.h>

#define CC 8
#define FF 1024
#define WW 512
#define HH 16
#define DD 64
#define FE 4096
#define EPS_ 1e-5f

typedef __attribute__((ext_vector_type(8))) short bf16x8;
typedef __attribute__((ext_vector_type(4))) float f32x4;

static __device__ __forceinline__ unsigned short f2bf(float f) {
    unsigned u = __float_as_uint(f);
    u += 0x7fffu + ((u >> 16) & 1u);          // round-to-nearest-even
    return (unsigned short)(u >> 16);
}
static __device__ __forceinline__ float bf2f(unsigned short h) {
    return __uint_as_float(((unsigned)h) << 16);
}
static __device__ __forceinline__ float gelu_exact(float v) {
    return 0.5f * v * (1.0f + erff(v * 0.70710678118654752f));
}

typedef const __attribute__((address_space(1))) unsigned int* gas_p;
typedef __attribute__((address_space(3))) unsigned int* las_p;
static __device__ __forceinline__ void gload_lds16(const void* g, void* l) {
    __builtin_amdgcn_global_load_lds((gas_p)g, (las_p)l, 16, 0, 0);
}

// ---------------------------------------------------------------------------
// frame_norm over F per (c,w) column, x (c,f,w) fp32 -> zt (c,w,f) bf16
// ---------------------------------------------------------------------------
__global__ __launch_bounds__(256) void frame_norm_t_k(
    const float* __restrict__ x, const float* __restrict__ g,
    const float* __restrict__ b, unsigned short* __restrict__ zt)
{
    int c  = blockIdx.y;
    int w0 = blockIdx.x * 64;
    int t  = threadIdx.x;
    int wl = t & 63;
    int fg = t >> 6;
    const float* xc = x + (size_t)c * FF * WW;

    float sum = 0.f, sq = 0.f;
    for (int f = fg; f < FF; f += 4) {
        float v = xc[(size_t)f * WW + w0 + wl];
        sum += v; sq += v * v;
    }
    __shared__ float ssum[4][64], ssq[4][64], smu[64], srv[64];
    ssum[fg][wl] = sum; ssq[fg][wl] = sq;
    __syncthreads();
    if (fg == 0) {
        float s = 0.f, q = 0.f;
        #pragma unroll
        for (int j = 0; j < 4; j++) { s += ssum[j][wl]; q += ssq[j][wl]; }
        float mu  = s * (1.f / FF);
        float var = q * (1.f / FF) - mu * mu;
        smu[wl] = mu;
        srv[wl] = rsqrtf(var + EPS_);
    }
    __syncthreads();
    float mu = smu[wl], rv = srv[wl];

    __shared__ float sT[64][65];
    unsigned short* ztc = zt + (size_t)c * WW * FF;
    for (int f0 = 0; f0 < FF; f0 += 64) {
        #pragma unroll
        for (int i = 0; i < 16; i++) {
            int fl = fg * 16 + i;
            int f  = f0 + fl;
            float v = xc[(size_t)f * WW + w0 + wl];
            sT[fl][wl] = (v - mu) * rv * g[f] + b[f];
        }
        __syncthreads();
        #pragma unroll
        for (int i = 0; i < 16; i++) {
            int wr = fg * 16 + i;
            ztc[(size_t)(w0 + wr) * FF + f0 + wl] = f2bf(sT[wl][wr]);
        }
        __syncthreads();
    }
}

// ---------------------------------------------------------------------------
// GEMM v2: Out[c,m,n] = sum_k A[c,m,k] * Bt[c,n,k], BN = 512 (full N).
// A fp32 weights (conv to bf16 in staging); Bt bf16 (C,512,K).
// 512 threads = 8 waves. BM=128: waves 2m x 4n (wave 64x128, 4x8 frags).
// BM=64: waves 1m x 8n (wave 64x64, 4x4 frags).
// Double-buffered LDS, one barrier per K-step. B staged by global_load_lds
// with slot-XOR involution swizzle (slot ^= row&3) on src AND read.
// Grid: 1-D, (M/BM)*8 blocks; c = bid&7 (XCD-resident channel), mt = bid>>3.
// mode 0: bf16 transposed out; 1: fp32 (c,m,n)+Add; 2: GELU bf16 transposed.
// ---------------------------------------------------------------------------
template<int BM>
__global__ __launch_bounds__(512) void gemm_v2_k(
    const float* __restrict__ A, const unsigned short* __restrict__ Bt,
    float* __restrict__ Outf, unsigned short* __restrict__ Outb,
    const float* __restrict__ Add, int M, int K, int mode)
{
    constexpr int NR = (BM == 128) ? 8 : 4;   // n-frags per wave
    constexpr int AP = 40;                    // A pitch (elems), 80 B

    int bid = blockIdx.x;
    int c   = bid & 7;
    int m0  = (bid >> 3) * BM;
    const float*          Ac = A  + (size_t)c * M * K;
    const unsigned short* Bc = Bt + (size_t)c * 512 * K;

    __shared__ unsigned short sA[2][BM * AP];
    __shared__ unsigned short sB[2][512 * 32];

    int t    = threadIdx.x;
    int lane = t & 63;
    int wid  = t >> 6;
    int frl  = lane & 15, fgr = lane >> 4;
    int wm   = (BM == 128) ? (wid >> 2) * 64 : 0;
    int wn   = (BM == 128) ? (wid & 3) * 128 : wid * 64;

    // B staging constants (per gload_lds call r: 16 rows x 64B granule-rows)
    int brow_in = (lane >> 2);                 // row within 16-row group
    int bslot   = (lane & 3) ^ ((lane >> 2) & 3);  // involution swizzle
    // A staging: row = t>>3 (+64 for BM=128), col = (t&7)*4
    int arow = t >> 3;
    int acol = (t & 7) * 4;

    f32x4 acc[4][NR];
    #pragma unroll
    for (int i = 0; i < 4; i++)
        #pragma unroll
        for (int j = 0; j < NR; j++) acc[i][j] = (f32x4){0.f, 0.f, 0.f, 0.f};

    float4 areg0, areg1;

    auto stageB = [&](int buf, int k0) {
        #pragma unroll
        for (int r = 0; r < 4; r++) {
            int row = r * 128 + wid * 16 + brow_in;
            gload_lds16(Bc + (size_t)row * K + k0 + bslot * 8,
                        &sB[buf][r * 4096 + wid * 512]);
        }
    };
    auto loadA = [&](int k0) {
        areg0 = *reinterpret_cast<const float4*>(
            Ac + (size_t)(m0 + arow) * K + k0 + acol);
        if constexpr (BM == 128)
            areg1 = *reinterpret_cast<const float4*>(
                Ac + (size_t)(m0 + arow + 64) * K + k0 + acol);
    };
    auto writeA = [&](int buf) {
        ushort4 h;
        h.x = f2bf(areg0.x); h.y = f2bf(areg0.y);
        h.z = f2bf(areg0.z); h.w = f2bf(areg0.w);
        *reinterpret_cast<ushort4*>(&sA[buf][arow * AP + acol]) = h;
        if constexpr (BM == 128) {
            ushort4 h2;
            h2.x = f2bf(areg1.x); h2.y = f2bf(areg1.y);
            h2.z = f2bf(areg1.z); h2.w = f2bf(areg1.w);
            *reinterpret_cast<ushort4*>(&sA[buf][(arow + 64) * AP + acol]) = h2;
        }
    };

    // prologue
    stageB(0, 0);
    loadA(0);
    writeA(0);
    __syncthreads();

    int NT = K >> 5;
    for (int kt = 0; kt < NT; ++kt) {
        int cur = kt & 1;
        if (kt + 1 < NT) {
            stageB(cur ^ 1, (kt + 1) * 32);
            loadA((kt + 1) * 32);
        }

        bf16x8 af[4], bfv[NR];
        #pragma unroll
        for (int mi = 0; mi < 4; mi++)
            af[mi] = *reinterpret_cast<const bf16x8*>(
                &sA[cur][(wm + mi * 16 + frl) * AP + fgr * 8]);
        #pragma unroll
        for (int ni = 0; ni < NR; ni++) {
            int row = wn + ni * 16 + frl;
            bfv[ni] = *reinterpret_cast<const bf16x8*>(
                &sB[cur][row * 32 + ((fgr ^ (frl & 3)) * 8)]);
        }
        #pragma unroll
        for (int mi = 0; mi < 4; mi++)
            #pragma unroll
            for (int ni = 0; ni < NR; ni++)
                acc[mi][ni] = __builtin_amdgcn_mfma_f32_16x16x32_bf16(
                    af[mi], bfv[ni], acc[mi][ni], 0, 0, 0);

        if (kt + 1 < NT) writeA(cur ^ 1);
        __syncthreads();
    }

    // epilogue. C/D: col = lane&15, row = (lane>>4)*4 + reg
    if (mode == 1) {
        #pragma unroll
        for (int mi = 0; mi < 4; mi++)
            #pragma unroll
            for (int ni = 0; ni < NR; ni++) {
                int mrow = m0 + wm + mi * 16 + fgr * 4;
                int ncol = wn + ni * 16 + frl;
                #pragma unroll
                for (int r = 0; r < 4; r++) {
                    size_t o = ((size_t)c * M + mrow + r) * 512 + ncol;
                    Outf[o] = acc[mi][ni][r] + Add[o];
                }
            }
    } else {
        bool gel = (mode == 2);
        #pragma unroll
        for (int mi = 0; mi < 4; mi++)
            #pragma unroll
            for (int ni = 0; ni < NR; ni++) {
                f32x4 v = acc[mi][ni];
                if (gel) {
                    v[0] = gelu_exact(v[0]); v[1] = gelu_exact(v[1]);
                    v[2] = gelu_exact(v[2]); v[3] = gelu_exact(v[3]);
                }
                int mrow = m0 + wm + mi * 16 + fgr * 4;
                int ncol = wn + ni * 16 + frl;
                ushort4 h;
                h.x = f2bf(v[0]); h.y = f2bf(v[1]);
                h.z = f2bf(v[2]); h.w = f2bf(v[3]);
                *reinterpret_cast<ushort4*>(
                    &Outb[((size_t)c * 512 + ncol) * M + mrow]) = h;
            }
    }
}

// ---------------------------------------------------------------------------
// MFMA flash attention (unchanged from round 3).
// ---------------------------------------------------------------------------
__global__ __launch_bounds__(256) void attn_mfma_k(
    const unsigned short* __restrict__ pt, const float* __restrict__ fr,
    unsigned short* __restrict__ ot)
{
    int ch = blockIdx.y;
    int c  = ch >> 4, h = ch & 15;
    int q0 = blockIdx.x * 64;
    int t  = threadIdx.x;
    int lane = t & 63;
    int wid  = t >> 6;
    int frl  = lane & 15, fgr = lane >> 4;

    const unsigned short* base = pt + (size_t)c * WW * FF + h * DD;

    __shared__ unsigned short Qs[64 * 72];
    __shared__ unsigned short Ks[64 * 72];
    __shared__ unsigned short Vt[64 * 72];
    __shared__ unsigned short Ps[4 * 16 * 72];

    {
        int kr = t >> 3, d0 = (t & 7) * 8;
        #pragma unroll
        for (int r = 0; r < 2; r++) {
            int row = kr + r * 32;
            int w   = q0 + row;
            bf16x8 v = *reinterpret_cast<const bf16x8*>(&base[(size_t)w * FF + d0]);
            bf16x8 o;
            if (d0 < 32) {
                #pragma unroll
                for (int j = 0; j < 8; j += 2) {
                    float x1 = bf2f((unsigned short)v[j]);
                    float x2 = bf2f((unsigned short)v[j + 1]);
                    float sn, cs;
                    __sincosf((float)w * fr[(d0 + j) >> 1], &sn, &cs);
                    o[j]     = (short)f2bf(x1 * cs - x2 * sn);
                    o[j + 1] = (short)f2bf(x2 * cs + x1 * sn);
                }
            } else o = v;
            *reinterpret_cast<bf16x8*>(&Qs[row * 72 + d0]) = o;
        }
    }

    f32x4 oacc[4];
    float m_[4], l_[4];
    #pragma unroll
    for (int i = 0; i < 4; i++) {
        oacc[i] = (f32x4){0.f, 0.f, 0.f, 0.f};
        m_[i] = -1e30f; l_[i] = 0.f;
    }
    unsigned short* myP = &Ps[wid * 16 * 72];
    int wq0 = wid * 16;

    for (int k0 = 0; k0 < WW; k0 += 64) {
        __syncthreads();
        {
            int kr = t >> 3, d0 = (t & 7) * 8;
            #pragma unroll
            for (int r = 0; r < 2; r++) {
                int row = kr + r * 32;
                int w   = k0 + row;
                bf16x8 v = *reinterpret_cast<const bf16x8*>(&base[(size_t)w * FF + d0]);
                bf16x8 o;
                if (d0 < 32) {
                    #pragma unroll
                    for (int j = 0; j < 8; j += 2) {
                        float x1 = bf2f((unsigned short)v[j]);
                        float x2 = bf2f((unsigned short)v[j + 1]);
                        float sn, cs;
                        __sincosf((float)w * fr[(d0 + j) >> 1], &sn, &cs);
                        o[j]     = (short)f2bf(x1 * cs - x2 * sn);
                        o[j + 1] = (short)f2bf(x2 * cs + x1 * sn);
                    }
                } else o = v;
                *reinterpret_cast<bf16x8*>(&Ks[row * 72 + d0]) = o;
            }
        }
        {
            int d  = t & 63;
            int kb = (t >> 6) * 8;
            #pragma unroll
            for (int r = 0; r < 2; r++) {
                int kk = kb + r * 32;
                bf16x8 o;
                #pragma unroll
                for (int j = 0; j < 8; j++)
                    o[j] = (short)base[(size_t)(k0 + kk + j) * FF + d];
                *reinterpret_cast<bf16x8*>(&Vt[d * 72 + kk]) = o;
            }
        }
        __syncthreads();

        f32x4 s[4];
        #pragma unroll
        for (int nt = 0; nt < 4; nt++) s[nt] = (f32x4){0.f, 0.f, 0.f, 0.f};
        bf16x8 aq0 = *reinterpret_cast<const bf16x8*>(&Qs[(wq0 + frl) * 72 + fgr * 8]);
        bf16x8 aq1 = *reinterpret_cast<const bf16x8*>(&Qs[(wq0 + frl) * 72 + 32 + fgr * 8]);
        #pragma unroll
        for (int nt = 0; nt < 4; nt++) {
            bf16x8 b0 = *reinterpret_cast<const bf16x8*>(&Ks[(nt * 16 + frl) * 72 + fgr * 8]);
            bf16x8 b1 = *reinterpret_cast<const bf16x8*>(&Ks[(nt * 16 + frl) * 72 + 32 + fgr * 8]);
            s[nt] = __builtin_amdgcn_mfma_f32_16x16x32_bf16(aq0, b0, s[nt], 0, 0, 0);
            s[nt] = __builtin_amdgcn_mfma_f32_16x16x32_bf16(aq1, b1, s[nt], 0, 0, 0);
        }

        #pragma unroll
        for (int r = 0; r < 4; r++) {
            float sv[4];
            #pragma unroll
            for (int nt = 0; nt < 4; nt++) sv[nt] = s[nt][r] * (1.f / 32.f);
            float mx = fmaxf(fmaxf(sv[0], sv[1]), fmaxf(sv[2], sv[3]));
            mx = fmaxf(mx, __shfl_xor(mx, 1, 64));
            mx = fmaxf(mx, __shfl_xor(mx, 2, 64));
            mx = fmaxf(mx, __shfl_xor(mx, 4, 64));
            mx = fmaxf(mx, __shfl_xor(mx, 8, 64));
            float mn    = fmaxf(m_[r], mx);
            float scale = __expf(m_[r] - mn);
            float rs = 0.f;
            #pragma unroll
            for (int nt = 0; nt < 4; nt++) {
                float p = __expf(sv[nt] - mn);
                myP[(fgr * 4 + r) * 72 + nt * 16 + frl] = f2bf(p);
                rs += p;
            }
            rs += __shfl_xor(rs, 1, 64);
            rs += __shfl_xor(rs, 2, 64);
            rs += __shfl_xor(rs, 4, 64);
            rs += __shfl_xor(rs, 8, 64);
            l_[r] = l_[r] * scale + rs;
            m_[r] = mn;
            #pragma unroll
            for (int dt = 0; dt < 4; dt++) oacc[dt][r] *= scale;
        }

        bf16x8 ap0 = *reinterpret_cast<const bf16x8*>(&myP[frl * 72 + fgr * 8]);
        bf16x8 ap1 = *reinterpret_cast<const bf16x8*>(&myP[frl * 72 + 32 + fgr * 8]);
        #pragma unroll
        for (int dt = 0; dt < 4; dt++) {
            bf16x8 b0 = *reinterpret_cast<const bf16x8*>(&Vt[(dt * 16 + frl) * 72 + fgr * 8]);
            bf16x8 b1 = *reinterpret_cast<const bf16x8*>(&Vt[(dt * 16 + frl) * 72 + 32 + fgr * 8]);
            oacc[dt] = __builtin_amdgcn_mfma_f32_16x16x32_bf16(ap0, b0, oacc[dt], 0, 0, 0);
            oacc[dt] = __builtin_amdgcn_mfma_f32_16x16x32_bf16(ap1, b1, oacc[dt], 0, 0, 0);
        }
    }

    unsigned short* ob = ot + (size_t)c * WW * FF + h * DD;
    #pragma unroll
    for (int r = 0; r < 4; r++) {
        float inv = 1.f / l_[r];
        int w = q0 + wq0 + fgr * 4 + r;
        #pragma unroll
        for (int dt = 0; dt < 4; dt++)
            ob[(size_t)w * FF + dt * 16 + frl] = f2bf(oacc[dt][r] * inv);
    }
}

// ---------------------------------------------------------------------------
extern "C" void kernel_launch(void* const* d_in, const int* in_sizes, int n_in,
                              void* d_out, int out_size, void* d_ws, size_t ws_size,
                              hipStream_t stream)
{
    const float* x  = (const float*)d_in[0];
    const float* g1 = (const float*)d_in[1];
    const float* b1 = (const float*)d_in[2];
    const float* wq = (const float*)d_in[3];
    const float* wo = (const float*)d_in[4];
    const float* fr = (const float*)d_in[5];
    const float* g2 = (const float*)d_in[6];
    const float* b2 = (const float*)d_in[7];
    const float* w1 = (const float*)d_in[8];
    const float* w2 = (const float*)d_in[9];

    const size_t SZ = (size_t)CC * FF * WW;
    char* wsb = (char*)d_ws;
    unsigned short* zt  = (unsigned short*)(wsb);            // bf16 (c,w,f)
    unsigned short* ptb = (unsigned short*)(wsb + 2 * SZ);   // bf16 (c,w,f)
    unsigned short* otb = (unsigned short*)(wsb + 4 * SZ);   // bf16 (c,w,f)
    float*          x2  = (float*)        (wsb + 6 * SZ);    // fp32 (c,f,w)
    unsigned short* h1t = (unsigned short*)(wsb + 10 * SZ);  // bf16 (c,w,4096)

    dim3 b256(256), b512(512);

    // 1. zt = frame_norm(x)^T (bf16)
    frame_norm_t_k<<<dim3(WW / 64, CC), b256, 0, stream>>>(x, g1, b1, zt);
    // 2. ptb = (wq . z)^T  — BM=64, grid (1024/64)*8 = 128
    gemm_v2_k<64><<<dim3(128), b512, 0, stream>>>(wq, zt, nullptr, ptb, nullptr, FF, FF, 0);
    // 3. attention (rope fused) -> otb (c,w,f) bf16
    attn_mfma_k<<<dim3(WW / 64, CC * HH), b256, 0, stream>>>(ptb, fr, otb);
    // 4. x2 = x + wo . o — BM=64
    gemm_v2_k<64><<<dim3(128), b512, 0, stream>>>(wo, otb, x2, nullptr, x, FF, FF, 1);
    // 5. zt = frame_norm(x2)^T
    frame_norm_t_k<<<dim3(WW / 64, CC), b256, 0, stream>>>(x2, g2, b2, zt);
    // 6. h1t = gelu(w1 . z2)^T — BM=128, grid (4096/128)*8 = 256
    gemm_v2_k<128><<<dim3(256), b512, 0, stream>>>(w1, zt, nullptr, h1t, nullptr, FE, FF, 2);
    // 7. out = x2 + w2 . h1 — BM=64, K=4096, grid (1024/64)*8 = 128
    gemm_v2_k<64><<<dim3(128), b512, 0, stream>>>(w2, h1t, (float*)d_out, nullptr, x2, FF, FE, 1);
}

// Round 5
// 436.124 us; speedup vs baseline: 9.1659x; 1.3265x over previous
//
#include <hip/hip_runtime.h>
#include <math.h>

#define CC 8
#define FF 1024
#define WW 512
#define HH 16
#define DD 64
#define FE 4096
#define EPS_ 1e-5f

typedef __attribute__((ext_vector_type(8))) short bf16x8;
typedef __attribute__((ext_vector_type(4))) float f32x4;

static __device__ __forceinline__ unsigned short f2bf(float f) {
    unsigned u = __float_as_uint(f);
    u += 0x7fffu + ((u >> 16) & 1u);          // round-to-nearest-even
    return (unsigned short)(u >> 16);
}
static __device__ __forceinline__ float bf2f(unsigned short h) {
    return __uint_as_float(((unsigned)h) << 16);
}
static __device__ __forceinline__ float gelu_exact(float v) {
    return 0.5f * v * (1.0f + erff(v * 0.70710678118654752f));
}

typedef const __attribute__((address_space(1))) unsigned int* gas_p;
typedef __attribute__((address_space(3))) unsigned int* las_p;
static __device__ __forceinline__ void gload_lds16(const void* g, void* l) {
    __builtin_amdgcn_global_load_lds((gas_p)g, (las_p)l, 16, 0, 0);
}

// ---------------------------------------------------------------------------
// frame_norm over F per (c,w) column, x (c,f,w) fp32 -> zt (c,w,f) bf16
// ---------------------------------------------------------------------------
__global__ __launch_bounds__(256) void frame_norm_t_k(
    const float* __restrict__ x, const float* __restrict__ g,
    const float* __restrict__ b, unsigned short* __restrict__ zt)
{
    int c  = blockIdx.y;
    int w0 = blockIdx.x * 64;
    int t  = threadIdx.x;
    int wl = t & 63;
    int fg = t >> 6;
    const float* xc = x + (size_t)c * FF * WW;

    float sum = 0.f, sq = 0.f;
    for (int f = fg; f < FF; f += 4) {
        float v = xc[(size_t)f * WW + w0 + wl];
        sum += v; sq += v * v;
    }
    __shared__ float ssum[4][64], ssq[4][64], smu[64], srv[64];
    ssum[fg][wl] = sum; ssq[fg][wl] = sq;
    __syncthreads();
    if (fg == 0) {
        float s = 0.f, q = 0.f;
        #pragma unroll
        for (int j = 0; j < 4; j++) { s += ssum[j][wl]; q += ssq[j][wl]; }
        float mu  = s * (1.f / FF);
        float var = q * (1.f / FF) - mu * mu;
        smu[wl] = mu;
        srv[wl] = rsqrtf(var + EPS_);
    }
    __syncthreads();
    float mu = smu[wl], rv = srv[wl];

    __shared__ float sT[64][65];
    unsigned short* ztc = zt + (size_t)c * WW * FF;
    for (int f0 = 0; f0 < FF; f0 += 64) {
        #pragma unroll
        for (int i = 0; i < 16; i++) {
            int fl = fg * 16 + i;
            int f  = f0 + fl;
            float v = xc[(size_t)f * WW + w0 + wl];
            sT[fl][wl] = (v - mu) * rv * g[f] + b[f];
        }
        __syncthreads();
        #pragma unroll
        for (int i = 0; i < 16; i++) {
            int wr = fg * 16 + i;
            ztc[(size_t)(w0 + wr) * FF + f0 + wl] = f2bf(sT[wl][wr]);
        }
        __syncthreads();
    }
}

// ---------------------------------------------------------------------------
// GEMM v3: Out[c,m,n] = sum_k A[c,m,k] * Bt[c,n,k]
// Tile 64m x 128n, BK=64, 256 thr = 4 waves of 32m x 64n (2x4 frags).
// Double-buffered LDS (~50 KB -> 3 blocks/CU). B via global_load_lds with
// slot-XOR involution swizzle (slot ^= row&7 on src AND read). A reg-staged
// fp32->bf16, pitch 72. Grid 1-D: bid = c + 8*(nt + 4*mt): the 4 n-blocks
// sharing an A panel are adjacent and XCD-pinned to channel c (L2 reuse).
// mode 0: bf16 transposed out; 1: fp32 (c,m,n)+Add; 2: GELU bf16 transposed.
// ---------------------------------------------------------------------------
__global__ __launch_bounds__(256, 3) void gemm_v3_k(
    const float* __restrict__ A, const unsigned short* __restrict__ Bt,
    float* __restrict__ Outf, unsigned short* __restrict__ Outb,
    const float* __restrict__ Add, int M, int K, int mode)
{
    int bid = blockIdx.x;
    int c   = bid & 7;
    int rem = bid >> 3;
    int nt  = rem & 3;
    int mt  = rem >> 2;
    int m0  = mt * 64, n0 = nt * 128;
    const float*          Ac = A  + (size_t)c * M * K;
    const unsigned short* Bc = Bt + ((size_t)c * 512 + n0) * K;

    __shared__ unsigned short sA[2][64 * 72];    // pitch 72 (144 B)
    __shared__ unsigned short sB[2][128 * 64];   // linear rows, slot-swizzled

    int t    = threadIdx.x;
    int lane = t & 63;
    int wid  = t >> 6;
    int frl  = lane & 15, fgr = lane >> 4;
    int WM   = (wid >> 1) * 32, WN = (wid & 1) * 64;

    f32x4 acc[2][4];
    #pragma unroll
    for (int i = 0; i < 2; i++)
        #pragma unroll
        for (int j = 0; j < 4; j++) acc[i][j] = (f32x4){0.f, 0.f, 0.f, 0.f};

    int arow = t >> 4;          // 0..15
    int acol = (t & 15) * 4;    // 0..60
    float4 ar[4];

    int bro   = lane >> 3;              // row-in-group 0..7
    int bslot = (lane & 7) ^ bro;       // involution swizzle

    auto loadA = [&](int k0) {
        #pragma unroll
        for (int p = 0; p < 4; p++)
            ar[p] = *reinterpret_cast<const float4*>(
                Ac + (size_t)(m0 + p * 16 + arow) * K + k0 + acol);
    };
    auto writeA = [&](int buf) {
        #pragma unroll
        for (int p = 0; p < 4; p++) {
            ushort4 h;
            h.x = f2bf(ar[p].x); h.y = f2bf(ar[p].y);
            h.z = f2bf(ar[p].z); h.w = f2bf(ar[p].w);
            *reinterpret_cast<ushort4*>(&sA[buf][(p * 16 + arow) * 72 + acol]) = h;
        }
    };
    auto stageB = [&](int buf, int k0) {
        #pragma unroll
        for (int r = 0; r < 4; r++) {
            int rbase = wid * 32 + r * 8;
            gload_lds16(Bc + (size_t)(rbase + bro) * K + k0 + bslot * 8,
                        &sB[buf][rbase * 64]);
        }
    };

    // prologue
    loadA(0);
    stageB(0, 0);
    writeA(0);
    __syncthreads();

    int NT = K >> 6;
    for (int kt = 0; kt < NT; ++kt) {
        int cur = kt & 1;
        if (kt + 1 < NT) {
            loadA((kt + 1) << 6);
            stageB(cur ^ 1, (kt + 1) << 6);
        }
        #pragma unroll
        for (int ks = 0; ks < 2; ks++) {
            bf16x8 af[2], bfv[4];
            #pragma unroll
            for (int mi = 0; mi < 2; mi++)
                af[mi] = *reinterpret_cast<const bf16x8*>(
                    &sA[cur][(WM + mi * 16 + frl) * 72 + ks * 32 + fgr * 8]);
            #pragma unroll
            for (int ni = 0; ni < 4; ni++) {
                int row  = WN + ni * 16 + frl;
                int slot = ((ks << 2) | fgr) ^ (frl & 7);
                bfv[ni] = *reinterpret_cast<const bf16x8*>(
                    &sB[cur][row * 64 + slot * 8]);
            }
            #pragma unroll
            for (int mi = 0; mi < 2; mi++)
                #pragma unroll
                for (int ni = 0; ni < 4; ni++)
                    acc[mi][ni] = __builtin_amdgcn_mfma_f32_16x16x32_bf16(
                        af[mi], bfv[ni], acc[mi][ni], 0, 0, 0);
        }
        if (kt + 1 < NT) writeA(cur ^ 1);
        __syncthreads();
    }

    // epilogue. C/D: col = lane&15, row = (lane>>4)*4 + reg
    if (mode == 1) {
        #pragma unroll
        for (int mi = 0; mi < 2; mi++)
            #pragma unroll
            for (int ni = 0; ni < 4; ni++) {
                int mrow = m0 + WM + mi * 16 + fgr * 4;
                int ncol = n0 + WN + ni * 16 + frl;
                #pragma unroll
                for (int r = 0; r < 4; r++) {
                    size_t o = ((size_t)c * M + mrow + r) * 512 + ncol;
                    Outf[o] = acc[mi][ni][r] + Add[o];
                }
            }
    } else {
        bool gel = (mode == 2);
        #pragma unroll
        for (int mi = 0; mi < 2; mi++)
            #pragma unroll
            for (int ni = 0; ni < 4; ni++) {
                f32x4 v = acc[mi][ni];
                if (gel) {
                    v[0] = gelu_exact(v[0]); v[1] = gelu_exact(v[1]);
                    v[2] = gelu_exact(v[2]); v[3] = gelu_exact(v[3]);
                }
                int mrow = m0 + WM + mi * 16 + fgr * 4;
                int ncol = n0 + WN + ni * 16 + frl;
                ushort4 h;
                h.x = f2bf(v[0]); h.y = f2bf(v[1]);
                h.z = f2bf(v[2]); h.w = f2bf(v[3]);
                *reinterpret_cast<ushort4*>(
                    &Outb[((size_t)c * 512 + ncol) * M + mrow]) = h;
            }
    }
}

// ---------------------------------------------------------------------------
// MFMA flash attention (unchanged from round 3).
// ---------------------------------------------------------------------------
__global__ __launch_bounds__(256) void attn_mfma_k(
    const unsigned short* __restrict__ pt, const float* __restrict__ fr,
    unsigned short* __restrict__ ot)
{
    int ch = blockIdx.y;
    int c  = ch >> 4, h = ch & 15;
    int q0 = blockIdx.x * 64;
    int t  = threadIdx.x;
    int lane = t & 63;
    int wid  = t >> 6;
    int frl  = lane & 15, fgr = lane >> 4;

    const unsigned short* base = pt + (size_t)c * WW * FF + h * DD;

    __shared__ unsigned short Qs[64 * 72];
    __shared__ unsigned short Ks[64 * 72];
    __shared__ unsigned short Vt[64 * 72];
    __shared__ unsigned short Ps[4 * 16 * 72];

    {
        int kr = t >> 3, d0 = (t & 7) * 8;
        #pragma unroll
        for (int r = 0; r < 2; r++) {
            int row = kr + r * 32;
            int w   = q0 + row;
            bf16x8 v = *reinterpret_cast<const bf16x8*>(&base[(size_t)w * FF + d0]);
            bf16x8 o;
            if (d0 < 32) {
                #pragma unroll
                for (int j = 0; j < 8; j += 2) {
                    float x1 = bf2f((unsigned short)v[j]);
                    float x2 = bf2f((unsigned short)v[j + 1]);
                    float sn, cs;
                    __sincosf((float)w * fr[(d0 + j) >> 1], &sn, &cs);
                    o[j]     = (short)f2bf(x1 * cs - x2 * sn);
                    o[j + 1] = (short)f2bf(x2 * cs + x1 * sn);
                }
            } else o = v;
            *reinterpret_cast<bf16x8*>(&Qs[row * 72 + d0]) = o;
        }
    }

    f32x4 oacc[4];
    float m_[4], l_[4];
    #pragma unroll
    for (int i = 0; i < 4; i++) {
        oacc[i] = (f32x4){0.f, 0.f, 0.f, 0.f};
        m_[i] = -1e30f; l_[i] = 0.f;
    }
    unsigned short* myP = &Ps[wid * 16 * 72];
    int wq0 = wid * 16;

    for (int k0 = 0; k0 < WW; k0 += 64) {
        __syncthreads();
        {
            int kr = t >> 3, d0 = (t & 7) * 8;
            #pragma unroll
            for (int r = 0; r < 2; r++) {
                int row = kr + r * 32;
                int w   = k0 + row;
                bf16x8 v = *reinterpret_cast<const bf16x8*>(&base[(size_t)w * FF + d0]);
                bf16x8 o;
                if (d0 < 32) {
                    #pragma unroll
                    for (int j = 0; j < 8; j += 2) {
                        float x1 = bf2f((unsigned short)v[j]);
                        float x2 = bf2f((unsigned short)v[j + 1]);
                        float sn, cs;
                        __sincosf((float)w * fr[(d0 + j) >> 1], &sn, &cs);
                        o[j]     = (short)f2bf(x1 * cs - x2 * sn);
                        o[j + 1] = (short)f2bf(x2 * cs + x1 * sn);
                    }
                } else o = v;
                *reinterpret_cast<bf16x8*>(&Ks[row * 72 + d0]) = o;
            }
        }
        {
            int d  = t & 63;
            int kb = (t >> 6) * 8;
            #pragma unroll
            for (int r = 0; r < 2; r++) {
                int kk = kb + r * 32;
                bf16x8 o;
                #pragma unroll
                for (int j = 0; j < 8; j++)
                    o[j] = (short)base[(size_t)(k0 + kk + j) * FF + d];
                *reinterpret_cast<bf16x8*>(&Vt[d * 72 + kk]) = o;
            }
        }
        __syncthreads();

        f32x4 s[4];
        #pragma unroll
        for (int nt = 0; nt < 4; nt++) s[nt] = (f32x4){0.f, 0.f, 0.f, 0.f};
        bf16x8 aq0 = *reinterpret_cast<const bf16x8*>(&Qs[(wq0 + frl) * 72 + fgr * 8]);
        bf16x8 aq1 = *reinterpret_cast<const bf16x8*>(&Qs[(wq0 + frl) * 72 + 32 + fgr * 8]);
        #pragma unroll
        for (int nt = 0; nt < 4; nt++) {
            bf16x8 b0 = *reinterpret_cast<const bf16x8*>(&Ks[(nt * 16 + frl) * 72 + fgr * 8]);
            bf16x8 b1 = *reinterpret_cast<const bf16x8*>(&Ks[(nt * 16 + frl) * 72 + 32 + fgr * 8]);
            s[nt] = __builtin_amdgcn_mfma_f32_16x16x32_bf16(aq0, b0, s[nt], 0, 0, 0);
            s[nt] = __builtin_amdgcn_mfma_f32_16x16x32_bf16(aq1, b1, s[nt], 0, 0, 0);
        }

        #pragma unroll
        for (int r = 0; r < 4; r++) {
            float sv[4];
            #pragma unroll
            for (int nt = 0; nt < 4; nt++) sv[nt] = s[nt][r] * (1.f / 32.f);
            float mx = fmaxf(fmaxf(sv[0], sv[1]), fmaxf(sv[2], sv[3]));
            mx = fmaxf(mx, __shfl_xor(mx, 1, 64));
            mx = fmaxf(mx, __shfl_xor(mx, 2, 64));
            mx = fmaxf(mx, __shfl_xor(mx, 4, 64));
            mx = fmaxf(mx, __shfl_xor(mx, 8, 64));
            float mn    = fmaxf(m_[r], mx);
            float scale = __expf(m_[r] - mn);
            float rs = 0.f;
            #pragma unroll
            for (int nt = 0; nt < 4; nt++) {
                float p = __expf(sv[nt] - mn);
                myP[(fgr * 4 + r) * 72 + nt * 16 + frl] = f2bf(p);
                rs += p;
            }
            rs += __shfl_xor(rs, 1, 64);
            rs += __shfl_xor(rs, 2, 64);
            rs += __shfl_xor(rs, 4, 64);
            rs += __shfl_xor(rs, 8, 64);
            l_[r] = l_[r] * scale + rs;
            m_[r] = mn;
            #pragma unroll
            for (int dt = 0; dt < 4; dt++) oacc[dt][r] *= scale;
        }

        bf16x8 ap0 = *reinterpret_cast<const bf16x8*>(&myP[frl * 72 + fgr * 8]);
        bf16x8 ap1 = *reinterpret_cast<const bf16x8*>(&myP[frl * 72 + 32 + fgr * 8]);
        #pragma unroll
        for (int dt = 0; dt < 4; dt++) {
            bf16x8 b0 = *reinterpret_cast<const bf16x8*>(&Vt[(dt * 16 + frl) * 72 + fgr * 8]);
            bf16x8 b1 = *reinterpret_cast<const bf16x8*>(&Vt[(dt * 16 + frl) * 72 + 32 + fgr * 8]);
            oacc[dt] = __builtin_amdgcn_mfma_f32_16x16x32_bf16(ap0, b0, oacc[dt], 0, 0, 0);
            oacc[dt] = __builtin_amdgcn_mfma_f32_16x16x32_bf16(ap1, b1, oacc[dt], 0, 0, 0);
        }
    }

    unsigned short* ob = ot + (size_t)c * WW * FF + h * DD;
    #pragma unroll
    for (int r = 0; r < 4; r++) {
        float inv = 1.f / l_[r];
        int w = q0 + wq0 + fgr * 4 + r;
        #pragma unroll
        for (int dt = 0; dt < 4; dt++)
            ob[(size_t)w * FF + dt * 16 + frl] = f2bf(oacc[dt][r] * inv);
    }
}

// ---------------------------------------------------------------------------
extern "C" void kernel_launch(void* const* d_in, const int* in_sizes, int n_in,
                              void* d_out, int out_size, void* d_ws, size_t ws_size,
                              hipStream_t stream)
{
    const float* x  = (const float*)d_in[0];
    const float* g1 = (const float*)d_in[1];
    const float* b1 = (const float*)d_in[2];
    const float* wq = (const float*)d_in[3];
    const float* wo = (const float*)d_in[4];
    const float* fr = (const float*)d_in[5];
    const float* g2 = (const float*)d_in[6];
    const float* b2 = (const float*)d_in[7];
    const float* w1 = (const float*)d_in[8];
    const float* w2 = (const float*)d_in[9];

    const size_t SZ = (size_t)CC * FF * WW;
    char* wsb = (char*)d_ws;
    unsigned short* zt  = (unsigned short*)(wsb);            // bf16 (c,w,f)
    unsigned short* ptb = (unsigned short*)(wsb + 2 * SZ);   // bf16 (c,w,f)
    unsigned short* otb = (unsigned short*)(wsb + 4 * SZ);   // bf16 (c,w,f)
    float*          x2  = (float*)        (wsb + 6 * SZ);    // fp32 (c,f,w)
    unsigned short* h1t = (unsigned short*)(wsb + 10 * SZ);  // bf16 (c,w,4096)

    dim3 b256(256);

    // 1. zt = frame_norm(x)^T (bf16)
    frame_norm_t_k<<<dim3(WW / 64, CC), b256, 0, stream>>>(x, g1, b1, zt);
    // 2. ptb = (wq . z)^T — grid 8c x 4nt x 16mt = 512
    gemm_v3_k<<<dim3(8 * 4 * (FF / 64)), b256, 0, stream>>>(
        wq, zt, nullptr, ptb, nullptr, FF, FF, 0);
    // 3. attention (rope fused) -> otb (c,w,f) bf16
    attn_mfma_k<<<dim3(WW / 64, CC * HH), b256, 0, stream>>>(ptb, fr, otb);
    // 4. x2 = x + wo . o — grid 512
    gemm_v3_k<<<dim3(8 * 4 * (FF / 64)), b256, 0, stream>>>(
        wo, otb, x2, nullptr, x, FF, FF, 1);
    // 5. zt = frame_norm(x2)^T
    frame_norm_t_k<<<dim3(WW / 64, CC), b256, 0, stream>>>(x2, g2, b2, zt);
    // 6. h1t = gelu(w1 . z2)^T — grid 8 x 4 x 64 = 2048
    gemm_v3_k<<<dim3(8 * 4 * (FE / 64)), b256, 0, stream>>>(
        w1, zt, nullptr, h1t, nullptr, FE, FF, 2);
    // 7. out = x2 + w2 . h1 — grid 512, K=4096
    gemm_v3_k<<<dim3(8 * 4 * (FF / 64)), b256, 0, stream>>>(
        w2, h1t, (float*)d_out, nullptr, x2, FF, FE, 1);
}

// Round 6
// 282.793 us; speedup vs baseline: 14.1357x; 1.5422x over previous
//
#include <hip/hip_runtime.h>
#include <math.h>

#define CC 8
#define FF 1024
#define WW 512
#define HH 16
#define DD 64
#define FE 4096
#define EPS_ 1e-5f

typedef __attribute__((ext_vector_type(8))) short bf16x8;
typedef __attribute__((ext_vector_type(4))) float f32x4;

static __device__ __forceinline__ unsigned short f2bf(float f) {
    unsigned u = __float_as_uint(f);
    u += 0x7fffu + ((u >> 16) & 1u);          // round-to-nearest-even
    return (unsigned short)(u >> 16);
}
static __device__ __forceinline__ float bf2f(unsigned short h) {
    return __uint_as_float(((unsigned)h) << 16);
}
static __device__ __forceinline__ float gelu_exact(float v) {
    return 0.5f * v * (1.0f + erff(v * 0.70710678118654752f));
}

typedef const __attribute__((address_space(1))) unsigned int* gas_p;
typedef __attribute__((address_space(3))) unsigned int* las_p;
static __device__ __forceinline__ void gload_lds16(const void* g, void* l) {
    __builtin_amdgcn_global_load_lds((gas_p)g, (las_p)l, 16, 0, 0);
}

// ---------------------------------------------------------------------------
// frame_norm stage 1: partial (sum, sumsq) per (c,w) over 128-f slabs.
// grid (W/64, F/128, C) = (8, 8, 8), block 256.
// part layout: float2[(c*W + w)*8 + fsplit]
// ---------------------------------------------------------------------------
__global__ __launch_bounds__(256) void fn_stats_k(
    const float* __restrict__ x, float2* __restrict__ part)
{
    int c  = blockIdx.z;
    int w0 = blockIdx.x * 64;
    int f0 = blockIdx.y * 128;
    int t  = threadIdx.x, wl = t & 63, fg = t >> 6;
    const float* xc = x + (size_t)c * FF * WW;

    float s = 0.f, q = 0.f;
    #pragma unroll 8
    for (int i = 0; i < 32; i++) {
        int f = f0 + fg + 4 * i;
        float v = xc[(size_t)f * WW + w0 + wl];
        s += v; q += v * v;
    }
    __shared__ float ss[4][64], sq_[4][64];
    ss[fg][wl] = s; sq_[fg][wl] = q;
    __syncthreads();
    if (fg == 0) {
        float S = 0.f, Q = 0.f;
        #pragma unroll
        for (int j = 0; j < 4; j++) { S += ss[j][wl]; Q += sq_[j][wl]; }
        part[((size_t)c * WW + w0 + wl) * 8 + blockIdx.y] = make_float2(S, Q);
    }
}

// ---------------------------------------------------------------------------
// frame_norm stage 2: finalize stats, normalize, transpose -> zt (c,w,f) bf16
// grid (W/64, F/64, C) = (8, 16, 8), block 256.
// ---------------------------------------------------------------------------
__global__ __launch_bounds__(256) void fn_apply_k(
    const float* __restrict__ x, const float2* __restrict__ part,
    const float* __restrict__ g, const float* __restrict__ b,
    unsigned short* __restrict__ zt)
{
    int c  = blockIdx.z;
    int w0 = blockIdx.x * 64;
    int f0 = blockIdx.y * 64;
    int t  = threadIdx.x, wl = t & 63, fg = t >> 6;

    __shared__ float smu[64], srv[64];
    __shared__ float sT[64][65];

    if (t < 64) {
        float S = 0.f, Q = 0.f;
        #pragma unroll
        for (int fs = 0; fs < 8; fs++) {
            float2 v = part[((size_t)c * WW + w0 + t) * 8 + fs];
            S += v.x; Q += v.y;
        }
        float mu  = S * (1.f / FF);
        float var = Q * (1.f / FF) - mu * mu;
        smu[t] = mu;
        srv[t] = rsqrtf(var + EPS_);
    }
    const float* xc = x + (size_t)c * FF * WW;
    #pragma unroll
    for (int i = 0; i < 16; i++) {
        int fl = fg * 16 + i;
        sT[fl][wl] = xc[(size_t)(f0 + fl) * WW + w0 + wl];
    }
    __syncthreads();

    unsigned short* ztc = zt + (size_t)c * WW * FF;
    float gv = g[f0 + wl], bv = b[f0 + wl];
    #pragma unroll
    for (int i = 0; i < 16; i++) {
        int wr = fg * 16 + i;
        ztc[(size_t)(w0 + wr) * FF + f0 + wl] =
            f2bf((sT[wl][wr] - smu[wr]) * srv[wr] * gv + bv);
    }
}

// ---------------------------------------------------------------------------
// GEMM v3: Out[c,m,n] = sum_k A[c,m,k] * Bt[c,n,k]   (unchanged, round 5)
// ---------------------------------------------------------------------------
__global__ __launch_bounds__(256, 3) void gemm_v3_k(
    const float* __restrict__ A, const unsigned short* __restrict__ Bt,
    float* __restrict__ Outf, unsigned short* __restrict__ Outb,
    const float* __restrict__ Add, int M, int K, int mode)
{
    int bid = blockIdx.x;
    int c   = bid & 7;
    int rem = bid >> 3;
    int nt  = rem & 3;
    int mt  = rem >> 2;
    int m0  = mt * 64, n0 = nt * 128;
    const float*          Ac = A  + (size_t)c * M * K;
    const unsigned short* Bc = Bt + ((size_t)c * 512 + n0) * K;

    __shared__ unsigned short sA[2][64 * 72];
    __shared__ unsigned short sB[2][128 * 64];

    int t    = threadIdx.x;
    int lane = t & 63;
    int wid  = t >> 6;
    int frl  = lane & 15, fgr = lane >> 4;
    int WM   = (wid >> 1) * 32, WN = (wid & 1) * 64;

    f32x4 acc[2][4];
    #pragma unroll
    for (int i = 0; i < 2; i++)
        #pragma unroll
        for (int j = 0; j < 4; j++) acc[i][j] = (f32x4){0.f, 0.f, 0.f, 0.f};

    int arow = t >> 4;
    int acol = (t & 15) * 4;
    float4 ar[4];

    int bro   = lane >> 3;
    int bslot = (lane & 7) ^ bro;

    auto loadA = [&](int k0) {
        #pragma unroll
        for (int p = 0; p < 4; p++)
            ar[p] = *reinterpret_cast<const float4*>(
                Ac + (size_t)(m0 + p * 16 + arow) * K + k0 + acol);
    };
    auto writeA = [&](int buf) {
        #pragma unroll
        for (int p = 0; p < 4; p++) {
            ushort4 h;
            h.x = f2bf(ar[p].x); h.y = f2bf(ar[p].y);
            h.z = f2bf(ar[p].z); h.w = f2bf(ar[p].w);
            *reinterpret_cast<ushort4*>(&sA[buf][(p * 16 + arow) * 72 + acol]) = h;
        }
    };
    auto stageB = [&](int buf, int k0) {
        #pragma unroll
        for (int r = 0; r < 4; r++) {
            int rbase = wid * 32 + r * 8;
            gload_lds16(Bc + (size_t)(rbase + bro) * K + k0 + bslot * 8,
                        &sB[buf][rbase * 64]);
        }
    };

    loadA(0);
    stageB(0, 0);
    writeA(0);
    __syncthreads();

    int NT = K >> 6;
    for (int kt = 0; kt < NT; ++kt) {
        int cur = kt & 1;
        if (kt + 1 < NT) {
            loadA((kt + 1) << 6);
            stageB(cur ^ 1, (kt + 1) << 6);
        }
        #pragma unroll
        for (int ks = 0; ks < 2; ks++) {
            bf16x8 af[2], bfv[4];
            #pragma unroll
            for (int mi = 0; mi < 2; mi++)
                af[mi] = *reinterpret_cast<const bf16x8*>(
                    &sA[cur][(WM + mi * 16 + frl) * 72 + ks * 32 + fgr * 8]);
            #pragma unroll
            for (int ni = 0; ni < 4; ni++) {
                int row  = WN + ni * 16 + frl;
                int slot = ((ks << 2) | fgr) ^ (frl & 7);
                bfv[ni] = *reinterpret_cast<const bf16x8*>(
                    &sB[cur][row * 64 + slot * 8]);
            }
            #pragma unroll
            for (int mi = 0; mi < 2; mi++)
                #pragma unroll
                for (int ni = 0; ni < 4; ni++)
                    acc[mi][ni] = __builtin_amdgcn_mfma_f32_16x16x32_bf16(
                        af[mi], bfv[ni], acc[mi][ni], 0, 0, 0);
        }
        if (kt + 1 < NT) writeA(cur ^ 1);
        __syncthreads();
    }

    if (mode == 1) {
        #pragma unroll
        for (int mi = 0; mi < 2; mi++)
            #pragma unroll
            for (int ni = 0; ni < 4; ni++) {
                int mrow = m0 + WM + mi * 16 + fgr * 4;
                int ncol = n0 + WN + ni * 16 + frl;
                #pragma unroll
                for (int r = 0; r < 4; r++) {
                    size_t o = ((size_t)c * M + mrow + r) * 512 + ncol;
                    Outf[o] = acc[mi][ni][r] + Add[o];
                }
            }
    } else {
        bool gel = (mode == 2);
        #pragma unroll
        for (int mi = 0; mi < 2; mi++)
            #pragma unroll
            for (int ni = 0; ni < 4; ni++) {
                f32x4 v = acc[mi][ni];
                if (gel) {
                    v[0] = gelu_exact(v[0]); v[1] = gelu_exact(v[1]);
                    v[2] = gelu_exact(v[2]); v[3] = gelu_exact(v[3]);
                }
                int mrow = m0 + WM + mi * 16 + fgr * 4;
                int ncol = n0 + WN + ni * 16 + frl;
                ushort4 h;
                h.x = f2bf(v[0]); h.y = f2bf(v[1]);
                h.z = f2bf(v[2]); h.w = f2bf(v[3]);
                *reinterpret_cast<ushort4*>(
                    &Outb[((size_t)c * 512 + ncol) * M + mrow]) = h;
            }
    }
}

// ---------------------------------------------------------------------------
// MFMA flash attention (unchanged from round 3).
// ---------------------------------------------------------------------------
__global__ __launch_bounds__(256) void attn_mfma_k(
    const unsigned short* __restrict__ pt, const float* __restrict__ fr,
    unsigned short* __restrict__ ot)
{
    int ch = blockIdx.y;
    int c  = ch >> 4, h = ch & 15;
    int q0 = blockIdx.x * 64;
    int t  = threadIdx.x;
    int lane = t & 63;
    int wid  = t >> 6;
    int frl  = lane & 15, fgr = lane >> 4;

    const unsigned short* base = pt + (size_t)c * WW * FF + h * DD;

    __shared__ unsigned short Qs[64 * 72];
    __shared__ unsigned short Ks[64 * 72];
    __shared__ unsigned short Vt[64 * 72];
    __shared__ unsigned short Ps[4 * 16 * 72];

    {
        int kr = t >> 3, d0 = (t & 7) * 8;
        #pragma unroll
        for (int r = 0; r < 2; r++) {
            int row = kr + r * 32;
            int w   = q0 + row;
            bf16x8 v = *reinterpret_cast<const bf16x8*>(&base[(size_t)w * FF + d0]);
            bf16x8 o;
            if (d0 < 32) {
                #pragma unroll
                for (int j = 0; j < 8; j += 2) {
                    float x1 = bf2f((unsigned short)v[j]);
                    float x2 = bf2f((unsigned short)v[j + 1]);
                    float sn, cs;
                    __sincosf((float)w * fr[(d0 + j) >> 1], &sn, &cs);
                    o[j]     = (short)f2bf(x1 * cs - x2 * sn);
                    o[j + 1] = (short)f2bf(x2 * cs + x1 * sn);
                }
            } else o = v;
            *reinterpret_cast<bf16x8*>(&Qs[row * 72 + d0]) = o;
        }
    }

    f32x4 oacc[4];
    float m_[4], l_[4];
    #pragma unroll
    for (int i = 0; i < 4; i++) {
        oacc[i] = (f32x4){0.f, 0.f, 0.f, 0.f};
        m_[i] = -1e30f; l_[i] = 0.f;
    }
    unsigned short* myP = &Ps[wid * 16 * 72];
    int wq0 = wid * 16;

    for (int k0 = 0; k0 < WW; k0 += 64) {
        __syncthreads();
        {
            int kr = t >> 3, d0 = (t & 7) * 8;
            #pragma unroll
            for (int r = 0; r < 2; r++) {
                int row = kr + r * 32;
                int w   = k0 + row;
                bf16x8 v = *reinterpret_cast<const bf16x8*>(&base[(size_t)w * FF + d0]);
                bf16x8 o;
                if (d0 < 32) {
                    #pragma unroll
                    for (int j = 0; j < 8; j += 2) {
                        float x1 = bf2f((unsigned short)v[j]);
                        float x2 = bf2f((unsigned short)v[j + 1]);
                        float sn, cs;
                        __sincosf((float)w * fr[(d0 + j) >> 1], &sn, &cs);
                        o[j]     = (short)f2bf(x1 * cs - x2 * sn);
                        o[j + 1] = (short)f2bf(x2 * cs + x1 * sn);
                    }
                } else o = v;
                *reinterpret_cast<bf16x8*>(&Ks[row * 72 + d0]) = o;
            }
        }
        {
            int d  = t & 63;
            int kb = (t >> 6) * 8;
            #pragma unroll
            for (int r = 0; r < 2; r++) {
                int kk = kb + r * 32;
                bf16x8 o;
                #pragma unroll
                for (int j = 0; j < 8; j++)
                    o[j] = (short)base[(size_t)(k0 + kk + j) * FF + d];
                *reinterpret_cast<bf16x8*>(&Vt[d * 72 + kk]) = o;
            }
        }
        __syncthreads();

        f32x4 s[4];
        #pragma unroll
        for (int nt = 0; nt < 4; nt++) s[nt] = (f32x4){0.f, 0.f, 0.f, 0.f};
        bf16x8 aq0 = *reinterpret_cast<const bf16x8*>(&Qs[(wq0 + frl) * 72 + fgr * 8]);
        bf16x8 aq1 = *reinterpret_cast<const bf16x8*>(&Qs[(wq0 + frl) * 72 + 32 + fgr * 8]);
        #pragma unroll
        for (int nt = 0; nt < 4; nt++) {
            bf16x8 b0 = *reinterpret_cast<const bf16x8*>(&Ks[(nt * 16 + frl) * 72 + fgr * 8]);
            bf16x8 b1 = *reinterpret_cast<const bf16x8*>(&Ks[(nt * 16 + frl) * 72 + 32 + fgr * 8]);
            s[nt] = __builtin_amdgcn_mfma_f32_16x16x32_bf16(aq0, b0, s[nt], 0, 0, 0);
            s[nt] = __builtin_amdgcn_mfma_f32_16x16x32_bf16(aq1, b1, s[nt], 0, 0, 0);
        }

        #pragma unroll
        for (int r = 0; r < 4; r++) {
            float sv[4];
            #pragma unroll
            for (int nt = 0; nt < 4; nt++) sv[nt] = s[nt][r] * (1.f / 32.f);
            float mx = fmaxf(fmaxf(sv[0], sv[1]), fmaxf(sv[2], sv[3]));
            mx = fmaxf(mx, __shfl_xor(mx, 1, 64));
            mx = fmaxf(mx, __shfl_xor(mx, 2, 64));
            mx = fmaxf(mx, __shfl_xor(mx, 4, 64));
            mx = fmaxf(mx, __shfl_xor(mx, 8, 64));
            float mn    = fmaxf(m_[r], mx);
            float scale = __expf(m_[r] - mn);
            float rs = 0.f;
            #pragma unroll
            for (int nt = 0; nt < 4; nt++) {
                float p = __expf(sv[nt] - mn);
                myP[(fgr * 4 + r) * 72 + nt * 16 + frl] = f2bf(p);
                rs += p;
            }
            rs += __shfl_xor(rs, 1, 64);
            rs += __shfl_xor(rs, 2, 64);
            rs += __shfl_xor(rs, 4, 64);
            rs += __shfl_xor(rs, 8, 64);
            l_[r] = l_[r] * scale + rs;
            m_[r] = mn;
            #pragma unroll
            for (int dt = 0; dt < 4; dt++) oacc[dt][r] *= scale;
        }

        bf16x8 ap0 = *reinterpret_cast<const bf16x8*>(&myP[frl * 72 + fgr * 8]);
        bf16x8 ap1 = *reinterpret_cast<const bf16x8*>(&myP[frl * 72 + 32 + fgr * 8]);
        #pragma unroll
        for (int dt = 0; dt < 4; dt++) {
            bf16x8 b0 = *reinterpret_cast<const bf16x8*>(&Vt[(dt * 16 + frl) * 72 + fgr * 8]);
            bf16x8 b1 = *reinterpret_cast<const bf16x8*>(&Vt[(dt * 16 + frl) * 72 + 32 + fgr * 8]);
            oacc[dt] = __builtin_amdgcn_mfma_f32_16x16x32_bf16(ap0, b0, oacc[dt], 0, 0, 0);
            oacc[dt] = __builtin_amdgcn_mfma_f32_16x16x32_bf16(ap1, b1, oacc[dt], 0, 0, 0);
        }
    }

    unsigned short* ob = ot + (size_t)c * WW * FF + h * DD;
    #pragma unroll
    for (int r = 0; r < 4; r++) {
        float inv = 1.f / l_[r];
        int w = q0 + wq0 + fgr * 4 + r;
        #pragma unroll
        for (int dt = 0; dt < 4; dt++)
            ob[(size_t)w * FF + dt * 16 + frl] = f2bf(oacc[dt][r] * inv);
    }
}

// ---------------------------------------------------------------------------
extern "C" void kernel_launch(void* const* d_in, const int* in_sizes, int n_in,
                              void* d_out, int out_size, void* d_ws, size_t ws_size,
                              hipStream_t stream)
{
    const float* x  = (const float*)d_in[0];
    const float* g1 = (const float*)d_in[1];
    const float* b1 = (const float*)d_in[2];
    const float* wq = (const float*)d_in[3];
    const float* wo = (const float*)d_in[4];
    const float* fr = (const float*)d_in[5];
    const float* g2 = (const float*)d_in[6];
    const float* b2 = (const float*)d_in[7];
    const float* w1 = (const float*)d_in[8];
    const float* w2 = (const float*)d_in[9];

    const size_t SZ = (size_t)CC * FF * WW;
    char* wsb = (char*)d_ws;
    unsigned short* zt  = (unsigned short*)(wsb);            // bf16 (c,w,f)
    unsigned short* ptb = (unsigned short*)(wsb + 2 * SZ);   // bf16 (c,w,f)
    unsigned short* otb = (unsigned short*)(wsb + 4 * SZ);   // bf16 (c,w,f)
    float*          x2  = (float*)        (wsb + 6 * SZ);    // fp32 (c,f,w)
    unsigned short* h1t = (unsigned short*)(wsb + 10 * SZ);  // bf16 (c,w,4096)
    float2*         prt = (float2*)       (wsb + 18 * SZ);   // stats partials

    dim3 b256(256);
    dim3 gst(WW / 64, FF / 128, CC);   // stats grid 512
    dim3 gap(WW / 64, FF / 64, CC);    // apply grid 1024

    // 1. zt = frame_norm(x)^T (bf16)
    fn_stats_k<<<gst, b256, 0, stream>>>(x, prt);
    fn_apply_k<<<gap, b256, 0, stream>>>(x, prt, g1, b1, zt);
    // 2. ptb = (wq . z)^T — grid 8c x 4nt x 16mt = 512
    gemm_v3_k<<<dim3(8 * 4 * (FF / 64)), b256, 0, stream>>>(
        wq, zt, nullptr, ptb, nullptr, FF, FF, 0);
    // 3. attention (rope fused) -> otb (c,w,f) bf16
    attn_mfma_k<<<dim3(WW / 64, CC * HH), b256, 0, stream>>>(ptb, fr, otb);
    // 4. x2 = x + wo . o — grid 512
    gemm_v3_k<<<dim3(8 * 4 * (FF / 64)), b256, 0, stream>>>(
        wo, otb, x2, nullptr, x, FF, FF, 1);
    // 5. zt = frame_norm(x2)^T
    fn_stats_k<<<gst, b256, 0, stream>>>(x2, prt);
    fn_apply_k<<<gap, b256, 0, stream>>>(x2, prt, g2, b2, zt);
    // 6. h1t = gelu(w1 . z2)^T — grid 8 x 4 x 64 = 2048
    gemm_v3_k<<<dim3(8 * 4 * (FE / 64)), b256, 0, stream>>>(
        w1, zt, nullptr, h1t, nullptr, FE, FF, 2);
    // 7. out = x2 + w2 . h1 — grid 512, K=4096
    gemm_v3_k<<<dim3(8 * 4 * (FF / 64)), b256, 0, stream>>>(
        w2, h1t, (float*)d_out, nullptr, x2, FF, FE, 1);
}

// Round 7
// 277.413 us; speedup vs baseline: 14.4098x; 1.0194x over previous
//
#include <hip/hip_runtime.h>
#include <math.h>

#define CC 8
#define FF 1024
#define WW 512
#define HH 16
#define DD 64
#define FE 4096
#define EPS_ 1e-5f

typedef __attribute__((ext_vector_type(8))) short bf16x8;
typedef __attribute__((ext_vector_type(4))) float f32x4;

static __device__ __forceinline__ unsigned short f2bf(float f) {
    unsigned u = __float_as_uint(f);
    u += 0x7fffu + ((u >> 16) & 1u);          // round-to-nearest-even
    return (unsigned short)(u >> 16);
}
static __device__ __forceinline__ float bf2f(unsigned short h) {
    return __uint_as_float(((unsigned)h) << 16);
}
static __device__ __forceinline__ float gelu_exact(float v) {
    return 0.5f * v * (1.0f + erff(v * 0.70710678118654752f));
}

typedef const __attribute__((address_space(1))) unsigned int* gas_p;
typedef __attribute__((address_space(3))) unsigned int* las_p;
static __device__ __forceinline__ void gload_lds16(const void* g, void* l) {
    __builtin_amdgcn_global_load_lds((gas_p)g, (las_p)l, 16, 0, 0);
}

// ---------------------------------------------------------------------------
// frame_norm stage 1: partial (sum, sumsq) per (c,w) over 128-f slabs.
// ---------------------------------------------------------------------------
__global__ __launch_bounds__(256) void fn_stats_k(
    const float* __restrict__ x, float2* __restrict__ part)
{
    int c  = blockIdx.z;
    int w0 = blockIdx.x * 64;
    int f0 = blockIdx.y * 128;
    int t  = threadIdx.x, wl = t & 63, fg = t >> 6;
    const float* xc = x + (size_t)c * FF * WW;

    float s = 0.f, q = 0.f;
    #pragma unroll 8
    for (int i = 0; i < 32; i++) {
        int f = f0 + fg + 4 * i;
        float v = xc[(size_t)f * WW + w0 + wl];
        s += v; q += v * v;
    }
    __shared__ float ss[4][64], sq_[4][64];
    ss[fg][wl] = s; sq_[fg][wl] = q;
    __syncthreads();
    if (fg == 0) {
        float S = 0.f, Q = 0.f;
        #pragma unroll
        for (int j = 0; j < 4; j++) { S += ss[j][wl]; Q += sq_[j][wl]; }
        part[((size_t)c * WW + w0 + wl) * 8 + blockIdx.y] = make_float2(S, Q);
    }
}

// ---------------------------------------------------------------------------
// frame_norm stage 2: finalize stats, normalize, transpose -> zt (c,w,f) bf16
// ---------------------------------------------------------------------------
__global__ __launch_bounds__(256) void fn_apply_k(
    const float* __restrict__ x, const float2* __restrict__ part,
    const float* __restrict__ g, const float* __restrict__ b,
    unsigned short* __restrict__ zt)
{
    int c  = blockIdx.z;
    int w0 = blockIdx.x * 64;
    int f0 = blockIdx.y * 64;
    int t  = threadIdx.x, wl = t & 63, fg = t >> 6;

    __shared__ float smu[64], srv[64];
    __shared__ float sT[64][65];

    if (t < 64) {
        float S = 0.f, Q = 0.f;
        #pragma unroll
        for (int fs = 0; fs < 8; fs++) {
            float2 v = part[((size_t)c * WW + w0 + t) * 8 + fs];
            S += v.x; Q += v.y;
        }
        float mu  = S * (1.f / FF);
        float var = Q * (1.f / FF) - mu * mu;
        smu[t] = mu;
        srv[t] = rsqrtf(var + EPS_);
    }
    const float* xc = x + (size_t)c * FF * WW;
    #pragma unroll
    for (int i = 0; i < 16; i++) {
        int fl = fg * 16 + i;
        sT[fl][wl] = xc[(size_t)(f0 + fl) * WW + w0 + wl];
    }
    __syncthreads();

    unsigned short* ztc = zt + (size_t)c * WW * FF;
    float gv = g[f0 + wl], bv = b[f0 + wl];
    #pragma unroll
    for (int i = 0; i < 16; i++) {
        int wr = fg * 16 + i;
        ztc[(size_t)(w0 + wr) * FF + f0 + wl] =
            f2bf((sT[wl][wr] - smu[wr]) * srv[wr] * gv + bv);
    }
}

// ---------------------------------------------------------------------------
// GEMM v3 (round-5, proven): 64m x 128n tile, BK=64, 4 waves of 32x64.
// Used for wq / wo / w2 (M = 1024 shapes).
// ---------------------------------------------------------------------------
__global__ __launch_bounds__(256, 3) void gemm_v3_k(
    const float* __restrict__ A, const unsigned short* __restrict__ Bt,
    float* __restrict__ Outf, unsigned short* __restrict__ Outb,
    const float* __restrict__ Add, int M, int K, int mode)
{
    int bid = blockIdx.x;
    int c   = bid & 7;
    int rem = bid >> 3;
    int nt  = rem & 3;
    int mt  = rem >> 2;
    int m0  = mt * 64, n0 = nt * 128;
    const float*          Ac = A  + (size_t)c * M * K;
    const unsigned short* Bc = Bt + ((size_t)c * 512 + n0) * K;

    __shared__ unsigned short sA[2][64 * 72];
    __shared__ unsigned short sB[2][128 * 64];

    int t    = threadIdx.x;
    int lane = t & 63;
    int wid  = t >> 6;
    int frl  = lane & 15, fgr = lane >> 4;
    int WM   = (wid >> 1) * 32, WN = (wid & 1) * 64;

    f32x4 acc[2][4];
    #pragma unroll
    for (int i = 0; i < 2; i++)
        #pragma unroll
        for (int j = 0; j < 4; j++) acc[i][j] = (f32x4){0.f, 0.f, 0.f, 0.f};

    int arow = t >> 4;
    int acol = (t & 15) * 4;
    float4 ar[4];

    int bro   = lane >> 3;
    int bslot = (lane & 7) ^ bro;

    auto loadA = [&](int k0) {
        #pragma unroll
        for (int p = 0; p < 4; p++)
            ar[p] = *reinterpret_cast<const float4*>(
                Ac + (size_t)(m0 + p * 16 + arow) * K + k0 + acol);
    };
    auto writeA = [&](int buf) {
        #pragma unroll
        for (int p = 0; p < 4; p++) {
            ushort4 h;
            h.x = f2bf(ar[p].x); h.y = f2bf(ar[p].y);
            h.z = f2bf(ar[p].z); h.w = f2bf(ar[p].w);
            *reinterpret_cast<ushort4*>(&sA[buf][(p * 16 + arow) * 72 + acol]) = h;
        }
    };
    auto stageB = [&](int buf, int k0) {
        #pragma unroll
        for (int r = 0; r < 4; r++) {
            int rbase = wid * 32 + r * 8;
            gload_lds16(Bc + (size_t)(rbase + bro) * K + k0 + bslot * 8,
                        &sB[buf][rbase * 64]);
        }
    };

    loadA(0);
    stageB(0, 0);
    writeA(0);
    __syncthreads();

    int NT = K >> 6;
    for (int kt = 0; kt < NT; ++kt) {
        int cur = kt & 1;
        if (kt + 1 < NT) {
            loadA((kt + 1) << 6);
            stageB(cur ^ 1, (kt + 1) << 6);
        }
        #pragma unroll
        for (int ks = 0; ks < 2; ks++) {
            bf16x8 af[2], bfv[4];
            #pragma unroll
            for (int mi = 0; mi < 2; mi++)
                af[mi] = *reinterpret_cast<const bf16x8*>(
                    &sA[cur][(WM + mi * 16 + frl) * 72 + ks * 32 + fgr * 8]);
            #pragma unroll
            for (int ni = 0; ni < 4; ni++) {
                int row  = WN + ni * 16 + frl;
                int slot = ((ks << 2) | fgr) ^ (frl & 7);
                bfv[ni] = *reinterpret_cast<const bf16x8*>(
                    &sB[cur][row * 64 + slot * 8]);
            }
            #pragma unroll
            for (int mi = 0; mi < 2; mi++)
                #pragma unroll
                for (int ni = 0; ni < 4; ni++)
                    acc[mi][ni] = __builtin_amdgcn_mfma_f32_16x16x32_bf16(
                        af[mi], bfv[ni], acc[mi][ni], 0, 0, 0);
        }
        if (kt + 1 < NT) writeA(cur ^ 1);
        __syncthreads();
    }

    if (mode == 1) {
        #pragma unroll
        for (int mi = 0; mi < 2; mi++)
            #pragma unroll
            for (int ni = 0; ni < 4; ni++) {
                int mrow = m0 + WM + mi * 16 + fgr * 4;
                int ncol = n0 + WN + ni * 16 + frl;
                #pragma unroll
                for (int r = 0; r < 4; r++) {
                    size_t o = ((size_t)c * M + mrow + r) * 512 + ncol;
                    Outf[o] = acc[mi][ni][r] + Add[o];
                }
            }
    } else {
        bool gel = (mode == 2);
        #pragma unroll
        for (int mi = 0; mi < 2; mi++)
            #pragma unroll
            for (int ni = 0; ni < 4; ni++) {
                f32x4 v = acc[mi][ni];
                if (gel) {
                    v[0] = gelu_exact(v[0]); v[1] = gelu_exact(v[1]);
                    v[2] = gelu_exact(v[2]); v[3] = gelu_exact(v[3]);
                }
                int mrow = m0 + WM + mi * 16 + fgr * 4;
                int ncol = n0 + WN + ni * 16 + frl;
                ushort4 h;
                h.x = f2bf(v[0]); h.y = f2bf(v[1]);
                h.z = f2bf(v[2]); h.w = f2bf(v[3]);
                *reinterpret_cast<ushort4*>(
                    &Outb[((size_t)c * 512 + ncol) * M + mrow]) = h;
            }
    }
}

// ---------------------------------------------------------------------------
// GEMM v4 for w1 (M=4096): 128m x 128n tile, BK=64, 4 waves of 64x64
// (4x4 frags, 32 MFMA/wave/iter = 2x MFMA per barrier-drain vs v3).
// LDS 69.6 KB dbuf -> 2 blocks/CU. B staging identical to v3. GELU + bf16
// transposed output (mode-2 epilogue only).
// Grid: bid = c + 8*(nt + 4*mt), mt over M/128.
// ---------------------------------------------------------------------------
__global__ __launch_bounds__(256, 2) void gemm_w1_k(
    const float* __restrict__ A, const unsigned short* __restrict__ Bt,
    unsigned short* __restrict__ Outb, int M, int K)
{
    int bid = blockIdx.x;
    int c   = bid & 7;
    int rem = bid >> 3;
    int nt  = rem & 3;
    int mt  = rem >> 2;
    int m0  = mt * 128, n0 = nt * 128;
    const float*          Ac = A  + (size_t)c * M * K;
    const unsigned short* Bc = Bt + ((size_t)c * 512 + n0) * K;

    __shared__ unsigned short sA[2][128 * 72];
    __shared__ unsigned short sB[2][128 * 64];

    int t    = threadIdx.x;
    int lane = t & 63;
    int wid  = t >> 6;
    int frl  = lane & 15, fgr = lane >> 4;
    int WM   = (wid >> 1) * 64, WN = (wid & 1) * 64;

    f32x4 acc[4][4];
    #pragma unroll
    for (int i = 0; i < 4; i++)
        #pragma unroll
        for (int j = 0; j < 4; j++) acc[i][j] = (f32x4){0.f, 0.f, 0.f, 0.f};

    int arow = t >> 4;          // 0..15
    int acol = (t & 15) * 4;    // 0..60
    float4 ar[8];

    int bro   = lane >> 3;
    int bslot = (lane & 7) ^ bro;

    auto loadA = [&](int k0) {
        #pragma unroll
        for (int p = 0; p < 8; p++)
            ar[p] = *reinterpret_cast<const float4*>(
                Ac + (size_t)(m0 + p * 16 + arow) * K + k0 + acol);
    };
    auto writeA = [&](int buf) {
        #pragma unroll
        for (int p = 0; p < 8; p++) {
            ushort4 h;
            h.x = f2bf(ar[p].x); h.y = f2bf(ar[p].y);
            h.z = f2bf(ar[p].z); h.w = f2bf(ar[p].w);
            *reinterpret_cast<ushort4*>(&sA[buf][(p * 16 + arow) * 72 + acol]) = h;
        }
    };
    auto stageB = [&](int buf, int k0) {
        #pragma unroll
        for (int r = 0; r < 4; r++) {
            int rbase = wid * 32 + r * 8;
            gload_lds16(Bc + (size_t)(rbase + bro) * K + k0 + bslot * 8,
                        &sB[buf][rbase * 64]);
        }
    };

    loadA(0);
    stageB(0, 0);
    writeA(0);
    __syncthreads();

    int NT = K >> 6;
    for (int kt = 0; kt < NT; ++kt) {
        int cur = kt & 1;
        if (kt + 1 < NT) {
            loadA((kt + 1) << 6);
            stageB(cur ^ 1, (kt + 1) << 6);
        }
        #pragma unroll
        for (int ks = 0; ks < 2; ks++) {
            bf16x8 af[4], bfv[4];
            #pragma unroll
            for (int mi = 0; mi < 4; mi++)
                af[mi] = *reinterpret_cast<const bf16x8*>(
                    &sA[cur][(WM + mi * 16 + frl) * 72 + ks * 32 + fgr * 8]);
            #pragma unroll
            for (int ni = 0; ni < 4; ni++) {
                int row  = WN + ni * 16 + frl;
                int slot = ((ks << 2) | fgr) ^ (frl & 7);
                bfv[ni] = *reinterpret_cast<const bf16x8*>(
                    &sB[cur][row * 64 + slot * 8]);
            }
            #pragma unroll
            for (int mi = 0; mi < 4; mi++)
                #pragma unroll
                for (int ni = 0; ni < 4; ni++)
                    acc[mi][ni] = __builtin_amdgcn_mfma_f32_16x16x32_bf16(
                        af[mi], bfv[ni], acc[mi][ni], 0, 0, 0);
        }
        if (kt + 1 < NT) writeA(cur ^ 1);
        __syncthreads();
    }

    // GELU + bf16 transposed (c,n,m) write. C/D: col=lane&15, row=(lane>>4)*4+reg
    #pragma unroll
    for (int mi = 0; mi < 4; mi++)
        #pragma unroll
        for (int ni = 0; ni < 4; ni++) {
            f32x4 v = acc[mi][ni];
            v[0] = gelu_exact(v[0]); v[1] = gelu_exact(v[1]);
            v[2] = gelu_exact(v[2]); v[3] = gelu_exact(v[3]);
            int mrow = m0 + WM + mi * 16 + fgr * 4;
            int ncol = n0 + WN + ni * 16 + frl;
            ushort4 h;
            h.x = f2bf(v[0]); h.y = f2bf(v[1]);
            h.z = f2bf(v[2]); h.w = f2bf(v[3]);
            *reinterpret_cast<ushort4*>(
                &Outb[((size_t)c * 512 + ncol) * M + mrow]) = h;
        }
}

// ---------------------------------------------------------------------------
// MFMA flash attention (unchanged from round 3).
// ---------------------------------------------------------------------------
__global__ __launch_bounds__(256) void attn_mfma_k(
    const unsigned short* __restrict__ pt, const float* __restrict__ fr,
    unsigned short* __restrict__ ot)
{
    int ch = blockIdx.y;
    int c  = ch >> 4, h = ch & 15;
    int q0 = blockIdx.x * 64;
    int t  = threadIdx.x;
    int lane = t & 63;
    int wid  = t >> 6;
    int frl  = lane & 15, fgr = lane >> 4;

    const unsigned short* base = pt + (size_t)c * WW * FF + h * DD;

    __shared__ unsigned short Qs[64 * 72];
    __shared__ unsigned short Ks[64 * 72];
    __shared__ unsigned short Vt[64 * 72];
    __shared__ unsigned short Ps[4 * 16 * 72];

    {
        int kr = t >> 3, d0 = (t & 7) * 8;
        #pragma unroll
        for (int r = 0; r < 2; r++) {
            int row = kr + r * 32;
            int w   = q0 + row;
            bf16x8 v = *reinterpret_cast<const bf16x8*>(&base[(size_t)w * FF + d0]);
            bf16x8 o;
            if (d0 < 32) {
                #pragma unroll
                for (int j = 0; j < 8; j += 2) {
                    float x1 = bf2f((unsigned short)v[j]);
                    float x2 = bf2f((unsigned short)v[j + 1]);
                    float sn, cs;
                    __sincosf((float)w * fr[(d0 + j) >> 1], &sn, &cs);
                    o[j]     = (short)f2bf(x1 * cs - x2 * sn);
                    o[j + 1] = (short)f2bf(x2 * cs + x1 * sn);
                }
            } else o = v;
            *reinterpret_cast<bf16x8*>(&Qs[row * 72 + d0]) = o;
        }
    }

    f32x4 oacc[4];
    float m_[4], l_[4];
    #pragma unroll
    for (int i = 0; i < 4; i++) {
        oacc[i] = (f32x4){0.f, 0.f, 0.f, 0.f};
        m_[i] = -1e30f; l_[i] = 0.f;
    }
    unsigned short* myP = &Ps[wid * 16 * 72];
    int wq0 = wid * 16;

    for (int k0 = 0; k0 < WW; k0 += 64) {
        __syncthreads();
        {
            int kr = t >> 3, d0 = (t & 7) * 8;
            #pragma unroll
            for (int r = 0; r < 2; r++) {
                int row = kr + r * 32;
                int w   = k0 + row;
                bf16x8 v = *reinterpret_cast<const bf16x8*>(&base[(size_t)w * FF + d0]);
                bf16x8 o;
                if (d0 < 32) {
                    #pragma unroll
                    for (int j = 0; j < 8; j += 2) {
                        float x1 = bf2f((unsigned short)v[j]);
                        float x2 = bf2f((unsigned short)v[j + 1]);
                        float sn, cs;
                        __sincosf((float)w * fr[(d0 + j) >> 1], &sn, &cs);
                        o[j]     = (short)f2bf(x1 * cs - x2 * sn);
                        o[j + 1] = (short)f2bf(x2 * cs + x1 * sn);
                    }
                } else o = v;
                *reinterpret_cast<bf16x8*>(&Ks[row * 72 + d0]) = o;
            }
        }
        {
            int d  = t & 63;
            int kb = (t >> 6) * 8;
            #pragma unroll
            for (int r = 0; r < 2; r++) {
                int kk = kb + r * 32;
                bf16x8 o;
                #pragma unroll
                for (int j = 0; j < 8; j++)
                    o[j] = (short)base[(size_t)(k0 + kk + j) * FF + d];
                *reinterpret_cast<bf16x8*>(&Vt[d * 72 + kk]) = o;
            }
        }
        __syncthreads();

        f32x4 s[4];
        #pragma unroll
        for (int nt = 0; nt < 4; nt++) s[nt] = (f32x4){0.f, 0.f, 0.f, 0.f};
        bf16x8 aq0 = *reinterpret_cast<const bf16x8*>(&Qs[(wq0 + frl) * 72 + fgr * 8]);
        bf16x8 aq1 = *reinterpret_cast<const bf16x8*>(&Qs[(wq0 + frl) * 72 + 32 + fgr * 8]);
        #pragma unroll
        for (int nt = 0; nt < 4; nt++) {
            bf16x8 b0 = *reinterpret_cast<const bf16x8*>(&Ks[(nt * 16 + frl) * 72 + fgr * 8]);
            bf16x8 b1 = *reinterpret_cast<const bf16x8*>(&Ks[(nt * 16 + frl) * 72 + 32 + fgr * 8]);
            s[nt] = __builtin_amdgcn_mfma_f32_16x16x32_bf16(aq0, b0, s[nt], 0, 0, 0);
            s[nt] = __builtin_amdgcn_mfma_f32_16x16x32_bf16(aq1, b1, s[nt], 0, 0, 0);
        }

        #pragma unroll
        for (int r = 0; r < 4; r++) {
            float sv[4];
            #pragma unroll
            for (int nt = 0; nt < 4; nt++) sv[nt] = s[nt][r] * (1.f / 32.f);
            float mx = fmaxf(fmaxf(sv[0], sv[1]), fmaxf(sv[2], sv[3]));
            mx = fmaxf(mx, __shfl_xor(mx, 1, 64));
            mx = fmaxf(mx, __shfl_xor(mx, 2, 64));
            mx = fmaxf(mx, __shfl_xor(mx, 4, 64));
            mx = fmaxf(mx, __shfl_xor(mx, 8, 64));
            float mn    = fmaxf(m_[r], mx);
            float scale = __expf(m_[r] - mn);
            float rs = 0.f;
            #pragma unroll
            for (int nt = 0; nt < 4; nt++) {
                float p = __expf(sv[nt] - mn);
                myP[(fgr * 4 + r) * 72 + nt * 16 + frl] = f2bf(p);
                rs += p;
            }
            rs += __shfl_xor(rs, 1, 64);
            rs += __shfl_xor(rs, 2, 64);
            rs += __shfl_xor(rs, 4, 64);
            rs += __shfl_xor(rs, 8, 64);
            l_[r] = l_[r] * scale + rs;
            m_[r] = mn;
            #pragma unroll
            for (int dt = 0; dt < 4; dt++) oacc[dt][r] *= scale;
        }

        bf16x8 ap0 = *reinterpret_cast<const bf16x8*>(&myP[frl * 72 + fgr * 8]);
        bf16x8 ap1 = *reinterpret_cast<const bf16x8*>(&myP[frl * 72 + 32 + fgr * 8]);
        #pragma unroll
        for (int dt = 0; dt < 4; dt++) {
            bf16x8 b0 = *reinterpret_cast<const bf16x8*>(&Vt[(dt * 16 + frl) * 72 + fgr * 8]);
            bf16x8 b1 = *reinterpret_cast<const bf16x8*>(&Vt[(dt * 16 + frl) * 72 + 32 + fgr * 8]);
            oacc[dt] = __builtin_amdgcn_mfma_f32_16x16x32_bf16(ap0, b0, oacc[dt], 0, 0, 0);
            oacc[dt] = __builtin_amdgcn_mfma_f32_16x16x32_bf16(ap1, b1, oacc[dt], 0, 0, 0);
        }
    }

    unsigned short* ob = ot + (size_t)c * WW * FF + h * DD;
    #pragma unroll
    for (int r = 0; r < 4; r++) {
        float inv = 1.f / l_[r];
        int w = q0 + wq0 + fgr * 4 + r;
        #pragma unroll
        for (int dt = 0; dt < 4; dt++)
            ob[(size_t)w * FF + dt * 16 + frl] = f2bf(oacc[dt][r] * inv);
    }
}

// ---------------------------------------------------------------------------
extern "C" void kernel_launch(void* const* d_in, const int* in_sizes, int n_in,
                              void* d_out, int out_size, void* d_ws, size_t ws_size,
                              hipStream_t stream)
{
    const float* x  = (const float*)d_in[0];
    const float* g1 = (const float*)d_in[1];
    const float* b1 = (const float*)d_in[2];
    const float* wq = (const float*)d_in[3];
    const float* wo = (const float*)d_in[4];
    const float* fr = (const float*)d_in[5];
    const float* g2 = (const float*)d_in[6];
    const float* b2 = (const float*)d_in[7];
    const float* w1 = (const float*)d_in[8];
    const float* w2 = (const float*)d_in[9];

    const size_t SZ = (size_t)CC * FF * WW;
    char* wsb = (char*)d_ws;
    unsigned short* zt  = (unsigned short*)(wsb);            // bf16 (c,w,f)
    unsigned short* ptb = (unsigned short*)(wsb + 2 * SZ);   // bf16 (c,w,f)
    unsigned short* otb = (unsigned short*)(wsb + 4 * SZ);   // bf16 (c,w,f)
    float*          x2  = (float*)        (wsb + 6 * SZ);    // fp32 (c,f,w)
    unsigned short* h1t = (unsigned short*)(wsb + 10 * SZ);  // bf16 (c,w,4096)
    float2*         prt = (float2*)       (wsb + 18 * SZ);   // stats partials

    dim3 b256(256);
    dim3 gst(WW / 64, FF / 128, CC);
    dim3 gap(WW / 64, FF / 64, CC);

    // 1. zt = frame_norm(x)^T (bf16)
    fn_stats_k<<<gst, b256, 0, stream>>>(x, prt);
    fn_apply_k<<<gap, b256, 0, stream>>>(x, prt, g1, b1, zt);
    // 2. ptb = (wq . z)^T
    gemm_v3_k<<<dim3(8 * 4 * (FF / 64)), b256, 0, stream>>>(
        wq, zt, nullptr, ptb, nullptr, FF, FF, 0);
    // 3. attention (rope fused) -> otb (c,w,f) bf16
    attn_mfma_k<<<dim3(WW / 64, CC * HH), b256, 0, stream>>>(ptb, fr, otb);
    // 4. x2 = x + wo . o
    gemm_v3_k<<<dim3(8 * 4 * (FF / 64)), b256, 0, stream>>>(
        wo, otb, x2, nullptr, x, FF, FF, 1);
    // 5. zt = frame_norm(x2)^T
    fn_stats_k<<<gst, b256, 0, stream>>>(x2, prt);
    fn_apply_k<<<gap, b256, 0, stream>>>(x2, prt, g2, b2, zt);
    // 6. h1t = gelu(w1 . z2)^T — 128x128 tile, grid 8 x 4 x 32 = 1024
    gemm_w1_k<<<dim3(8 * 4 * (FE / 128)), b256, 0, stream>>>(
        w1, zt, h1t, FE, FF);
    // 7. out = x2 + w2 . h1 — grid 512, K=4096
    gemm_v3_k<<<dim3(8 * 4 * (FF / 64)), b256, 0, stream>>>(
        w2, h1t, (float*)d_out, nullptr, x2, FF, FE, 1);
}